// Round 4
// baseline (231.256 us; speedup 1.0000x reference)
//
#include <hip/hip_runtime.h>
#include <math.h>

#define NQ 10
#define NL 3
#define PI_F 3.14159265358979f
#define EPB 4          // batch elements per block, one full wave (64 threads) each
#define TPB 256
#define CSLOTS 1056    // 1024 complex amps + pad (slot = k + (k>>5)), max 1054

// Composed CNOT-ring permutation (GF(2)-linear). Evaluated only at
// compile-time literals -> pure constants in the emitted code.
__host__ __device__ constexpr int cnot_chain_ce(int j) {
    for (int i = NQ - 1; i >= 0; --i) {
        int tq = (i + 1) % NQ;
        j ^= ((j >> (NQ - 1 - i)) & 1) << (NQ - 1 - tq);
    }
    return j;
}

#define FORALL16(F) F(0) F(1) F(2) F(3) F(4) F(5) F(6) F(7) \
                    F(8) F(9) F(10) F(11) F(12) F(13) F(14) F(15)
#define FORALLQ(F) F(0) F(1) F(2) F(3) F(4) F(5) F(6) F(7) F(8) F(9)

// ---- named register state: cr0..cr15 / ci0..ci15 (no arrays -> no scratch)
#define DECL_AMP(n) float cr##n, ci##n;
#define DECL_F(q) float f0_##q, f1_##q;

// 2x2 complex gate on one register pair
#define GP(p0, p1, g0, g1) {                                                  \
    float s0r_ = cr##p0, s0i_ = ci##p0, s1r_ = cr##p1, s1i_ = ci##p1;         \
    cr##p0 = g0.x * s0r_ - g0.y * s0i_ + g0.z * s1r_ - g0.w * s1i_;           \
    ci##p0 = g0.x * s0i_ + g0.y * s0r_ + g0.z * s1i_ + g0.w * s1r_;           \
    cr##p1 = g1.x * s0r_ - g1.y * s0i_ + g1.z * s1r_ - g1.w * s1i_;           \
    ci##p1 = g1.x * s0i_ + g1.y * s0r_ + g1.z * s1i_ + g1.w * s1r_; }

#define GATE_BIT3(g0,g1) GP(0,8,g0,g1) GP(1,9,g0,g1) GP(2,10,g0,g1) GP(3,11,g0,g1) \
                         GP(4,12,g0,g1) GP(5,13,g0,g1) GP(6,14,g0,g1) GP(7,15,g0,g1)
#define GATE_BIT2(g0,g1) GP(0,4,g0,g1) GP(1,5,g0,g1) GP(2,6,g0,g1) GP(3,7,g0,g1) \
                         GP(8,12,g0,g1) GP(9,13,g0,g1) GP(10,14,g0,g1) GP(11,15,g0,g1)
#define GATE_BIT1(g0,g1) GP(0,2,g0,g1) GP(1,3,g0,g1) GP(4,6,g0,g1) GP(5,7,g0,g1) \
                         GP(8,10,g0,g1) GP(9,11,g0,g1) GP(12,14,g0,g1) GP(13,15,g0,g1)
#define GATE_BIT0(g0,g1) GP(0,1,g0,g1) GP(2,3,g0,g1) GP(4,5,g0,g1) GP(6,7,g0,g1) \
                         GP(8,9,g0,g1) GP(10,11,g0,g1) GP(12,13,g0,g1) GP(14,15,g0,g1)

// cross-lane gate on lane-bit MK_ (xor-shuffle); lo lane uses row g0,
// hi lane uses row g1 with columns swapped so "mine" coeff comes first
#define SG(n) { float pr_ = __shfl_xor(cr##n, MK_, 64);                       \
                float pi_ = __shfl_xor(ci##n, MK_, 64);                       \
                float xr_ = cr##n, xi_ = ci##n;                               \
                cr##n = A_ * xr_ - B_ * xi_ + C_ * pr_ - D_ * pi_;            \
                ci##n = A_ * xi_ + B_ * xr_ + C_ * pi_ + D_ * pr_; }
#define SHFL_GATE(mask, g0, g1) {                                             \
    const int MK_ = (mask);                                                   \
    const bool hi_ = (t & (mask)) != 0;                                       \
    const float A_ = hi_ ? g1.z : g0.x;                                       \
    const float B_ = hi_ ? g1.w : g0.y;                                       \
    const float C_ = hi_ ? g1.x : g0.z;                                       \
    const float D_ = hi_ ? g1.y : g0.w;                                       \
    FORALL16(SG) }

// encoding factor pair per qubit, Pt-bit selection folded in
#define MKF(q) { float xv_ = xb[q];                                           \
    float ex_ = __expf(2.0f * xv_);                                           \
    float h_ = (1.0f - 2.0f / (ex_ + 1.0f)) * (PI_F * 0.5f);                  \
    float s_ = __sinf(h_), c_ = __cosf(h_);                                   \
    bool bt_ = (Pt >> (9 - q)) & 1;                                           \
    f0_##q = bt_ ? s_ : c_;                                                   \
    f1_##q = bt_ ? c_ : s_; }

// layer-0 amplitudes: P(j) for j<16 only touches qubits {0,1,6,7,8,9};
// bits: pos0=b0^b1 (q9), pos1=b1^b2 (q8), pos2=b2^b3 (q7), pos3=b3 (q6),
// pos8=pos9=b0 (q1,q0). amp = base(b0) * F6(b3)*F7(b2^b3)*F8(b1^b2)*F9(b0^b1)
#define INIT_AMP(J) {                                                         \
    constexpr int j_ = (J);                                                   \
    cr##J = ((j_ & 1) ? u1_ : u0_)                                            \
          * (((j_ >> 3) & 1) ? f1_6 : f0_6)                                   \
          * ((((j_ >> 2) ^ (j_ >> 3)) & 1) ? f1_7 : f0_7)                     \
          * ((((j_ >> 1) ^ (j_ >> 2)) & 1) ? f1_8 : f0_8)                     \
          * (((j_ ^ (j_ >> 1)) & 1) ? f1_9 : f0_9);                           \
    ci##J = 0.0f; }

// phase-A gather with ring permutation fused (pj_ is a compile-time constant)
#define GAT(n) { constexpr int pj_ = cnot_chain_ce(n);                        \
    const int pk_ = Pt ^ pj_;                                                 \
    float2 v_ = st[e][pk_ + (pk_ >> 5)];                                      \
    cr##n = v_.x; ci##n = v_.y; }

#define STA(n) st[e][baseA + n] = make_float2(cr##n, ci##n);
#define RDB(n) { float2 v_ = st[e][n * 66 + boff]; cr##n = v_.x; ci##n = v_.y; }
#define WRB(n) st[e][n * 66 + boff] = make_float2(cr##n, ci##n);

#define RED(n) { float p_ = cr##n * cr##n + ci##n * ci##n; S_ += p_;          \
    w0 += (((n) >> 3) & 1) ? -p_ : p_;                                        \
    w1 += (((n) >> 2) & 1) ? -p_ : p_;                                        \
    w2 += (((n) >> 1) & 1) ? -p_ : p_;                                        \
    w3 += ((n) & 1) ? -p_ : p_; }

#define WRED(v) { v += __shfl_xor(v, 1, 64);  v += __shfl_xor(v, 2, 64);      \
                  v += __shfl_xor(v, 4, 64);  v += __shfl_xor(v, 8, 64);      \
                  v += __shfl_xor(v, 16, 64); v += __shfl_xor(v, 32, 64); }

__global__ __launch_bounds__(TPB, 4)
__attribute__((amdgpu_waves_per_eu(4, 4)))
void vq_main(const float* __restrict__ x, const float* __restrict__ w,
             float* __restrict__ out) {
    __shared__ float2 st[EPB][CSLOTS];
    __shared__ float4 msh[NL * NQ * 2];   // 30 fused gate matrices

    const int tid = threadIdx.x;
    const int e = tid >> 6;        // batch sub-element (one wave each)
    const int t = tid & 63;        // lane within element
    const int b = blockIdx.x * EPB + e;

    // ---- fused M = Rz(c)*Ry(b)*Rx(a) per (layer,qubit), one thread each
    if (tid < NL * NQ) {
        const float* wp = w + tid * 3;
        float sa = __sinf(wp[0] * 0.5f), ca = __cosf(wp[0] * 0.5f);
        float sb = __sinf(wp[1] * 0.5f), cb = __cosf(wp[1] * 0.5f);
        float sc = __sinf(wp[2] * 0.5f), cc = __cosf(wp[2] * 0.5f);
        float c00r = cb * ca,  c00i =  sa * sb;
        float c01r = -sb * ca, c01i = -cb * sa;
        float c10r =  sb * ca, c10i = -cb * sa;
        float c11r =  cb * ca, c11i = -sb * sa;
        float4 m0, m1;
        m0.x = cc * c00r + sc * c00i;  m0.y = cc * c00i - sc * c00r;
        m0.z = cc * c01r + sc * c01i;  m0.w = cc * c01i - sc * c01r;
        m1.x = cc * c10r - sc * c10i;  m1.y = cc * c10i + sc * c10r;
        m1.z = cc * c11r - sc * c11i;  m1.w = cc * c11i + sc * c11r;
        msh[tid * 2] = m0;
        msh[tid * 2 + 1] = m1;
    }

    // P(t<<4): lane bit m is k-bit 4+m (phase A: k = t*16 + j)
    int Pt = 0;
#pragma unroll
    for (int m = 0; m < 6; ++m)
        Pt ^= ((t >> m) & 1) ? cnot_chain_ce(1 << (4 + m)) : 0;

    // wave-uniform x row -> scalar loads
    const int bu = __builtin_amdgcn_readfirstlane(b);
    const float* xb = x + bu * NQ;

    FORALLQ(DECL_F)
    FORALLQ(MKF)

    FORALL16(DECL_AMP)
    {
        float com_ = f0_2 * f0_3 * f0_4 * f0_5;
        float u0_ = f0_0 * f0_1 * com_;
        float u1_ = f1_0 * f1_1 * com_;
        FORALL16(INIT_AMP)
    }

    __syncthreads();   // msh ready

#pragma unroll 1
    for (int l = 0; l < NL; ++l) {
        if (l > 0) {
            FORALL16(GAT)
            __syncthreads();   // all gathers done before phase-A stores
        }
        // phase A: qubits 6..9 on j-bits 3..0
        { float4 g0 = msh[(l * NQ + 6) * 2], g1 = msh[(l * NQ + 6) * 2 + 1]; GATE_BIT3(g0, g1) }
        { float4 g0 = msh[(l * NQ + 7) * 2], g1 = msh[(l * NQ + 7) * 2 + 1]; GATE_BIT2(g0, g1) }
        { float4 g0 = msh[(l * NQ + 8) * 2], g1 = msh[(l * NQ + 8) * 2 + 1]; GATE_BIT1(g0, g1) }
        { float4 g0 = msh[(l * NQ + 9) * 2], g1 = msh[(l * NQ + 9) * 2 + 1]; GATE_BIT0(g0, g1) }
        // qubits 4,5 on lane bits 1,0 (k bits 5,4)
        { float4 g0 = msh[(l * NQ + 4) * 2], g1 = msh[(l * NQ + 4) * 2 + 1]; SHFL_GATE(2, g0, g1) }
        { float4 g0 = msh[(l * NQ + 5) * 2], g1 = msh[(l * NQ + 5) * 2 + 1]; SHFL_GATE(1, g0, g1) }
        // store phase-A layout: k = t*16+j -> slot k + (k>>5)
        {
            const int baseA = t * 16 + (t >> 1);
            FORALL16(STA)
        }
        __syncthreads();
        // phase B: amp i holds k = i*64 + t
        {
            const int boff = t + (t >> 5);
            FORALL16(RDB)
        }
        { float4 g0 = msh[(l * NQ + 0) * 2], g1 = msh[(l * NQ + 0) * 2 + 1]; GATE_BIT3(g0, g1) }
        { float4 g0 = msh[(l * NQ + 1) * 2], g1 = msh[(l * NQ + 1) * 2 + 1]; GATE_BIT2(g0, g1) }
        { float4 g0 = msh[(l * NQ + 2) * 2], g1 = msh[(l * NQ + 2) * 2 + 1]; GATE_BIT1(g0, g1) }
        { float4 g0 = msh[(l * NQ + 3) * 2], g1 = msh[(l * NQ + 3) * 2 + 1]; GATE_BIT0(g0, g1) }
        if (l < NL - 1) {
            const int boff = t + (t >> 5);
            FORALL16(WRB)      // same slots this lane just read -> no barrier first
            __syncthreads();
        }
    }

    // ---- readout from phase-B registers: k = i*64 + t
    float S_ = 0.0f, w0 = 0.0f, w1 = 0.0f, w2 = 0.0f, w3 = 0.0f;
    FORALL16(RED)
    float w4 = ((t >> 5) & 1) ? -S_ : S_;
    float w5 = ((t >> 4) & 1) ? -S_ : S_;
    float w6 = ((t >> 3) & 1) ? -S_ : S_;
    float w7 = ((t >> 2) & 1) ? -S_ : S_;
    float w8 = ((t >> 1) & 1) ? -S_ : S_;
    float w9 = (t & 1) ? -S_ : S_;

    WRED(w0) WRED(w1) WRED(w2) WRED(w3) WRED(w4)
    WRED(w5) WRED(w6) WRED(w7) WRED(w8) WRED(w9)

    if (t == 0) {
        float* op = out + b * NQ;
        op[0] = w0; op[1] = w1; op[2] = w2; op[3] = w3; op[4] = w4;
        op[5] = w5; op[6] = w6; op[7] = w7; op[8] = w8; op[9] = w9;
    }
}

extern "C" void kernel_launch(void* const* d_in, const int* in_sizes, int n_in,
                              void* d_out, int out_size, void* d_ws, size_t ws_size,
                              hipStream_t stream) {
    const float* x = (const float*)d_in[0];   // (16384, 10) fp32
    const float* w = (const float*)d_in[1];   // (3, 10, 3) fp32
    float* out = (float*)d_out;               // (16384, 10) fp32
    const int B = in_sizes[0] / NQ;           // 16384
    vq_main<<<dim3(B / EPB), dim3(TPB), 0, stream>>>(x, w, out);
}

// Round 5
// 215.226 us; speedup vs baseline: 1.0745x; 1.0745x over previous
//
#include <hip/hip_runtime.h>
#include <math.h>

#define NQ 10
#define NL 3
#define PI_F 3.14159265358979f
#define EPB 4          // batch elements per block, one full wave (64 threads) each
#define TPB 256
#define CSLOTS 1056    // 1024 complex amps + pad (slot = k + (k>>5)), max 1054

// Composed CNOT-ring permutation (GF(2)-linear). Evaluated only at
// compile-time literals -> pure constants in the emitted code.
__host__ __device__ constexpr int cnot_chain_ce(int j) {
    for (int i = NQ - 1; i >= 0; --i) {
        int tq = (i + 1) % NQ;
        j ^= ((j >> (NQ - 1 - i)) & 1) << (NQ - 1 - tq);
    }
    return j;
}

#define FORALL16(F) F(0) F(1) F(2) F(3) F(4) F(5) F(6) F(7) \
                    F(8) F(9) F(10) F(11) F(12) F(13) F(14) F(15)
#define FORALLQ(F) F(0) F(1) F(2) F(3) F(4) F(5) F(6) F(7) F(8) F(9)

// ---- named register state: cr0..cr15 / ci0..ci15 (no arrays -> no alloca)
#define DECL_AMP(n) float cr##n, ci##n;
#define DECL_F(q) float f0_##q, f1_##q;

// 2x2 complex gate on one register pair; g0/g1 are SGPR-resident (uniform)
#define GP(p0, p1, g0, g1) {                                                  \
    float s0r_ = cr##p0, s0i_ = ci##p0, s1r_ = cr##p1, s1i_ = ci##p1;         \
    cr##p0 = g0.x * s0r_ - g0.y * s0i_ + g0.z * s1r_ - g0.w * s1i_;           \
    ci##p0 = g0.x * s0i_ + g0.y * s0r_ + g0.z * s1i_ + g0.w * s1r_;           \
    cr##p1 = g1.x * s0r_ - g1.y * s0i_ + g1.z * s1r_ - g1.w * s1i_;           \
    ci##p1 = g1.x * s0i_ + g1.y * s0r_ + g1.z * s1i_ + g1.w * s1r_; }

#define GATE_BIT3(g0,g1) GP(0,8,g0,g1) GP(1,9,g0,g1) GP(2,10,g0,g1) GP(3,11,g0,g1) \
                         GP(4,12,g0,g1) GP(5,13,g0,g1) GP(6,14,g0,g1) GP(7,15,g0,g1)
#define GATE_BIT2(g0,g1) GP(0,4,g0,g1) GP(1,5,g0,g1) GP(2,6,g0,g1) GP(3,7,g0,g1) \
                         GP(8,12,g0,g1) GP(9,13,g0,g1) GP(10,14,g0,g1) GP(11,15,g0,g1)
#define GATE_BIT1(g0,g1) GP(0,2,g0,g1) GP(1,3,g0,g1) GP(4,6,g0,g1) GP(5,7,g0,g1) \
                         GP(8,10,g0,g1) GP(9,11,g0,g1) GP(12,14,g0,g1) GP(13,15,g0,g1)
#define GATE_BIT0(g0,g1) GP(0,1,g0,g1) GP(2,3,g0,g1) GP(4,5,g0,g1) GP(6,7,g0,g1) \
                         GP(8,9,g0,g1) GP(10,11,g0,g1) GP(12,13,g0,g1) GP(14,15,g0,g1)

// cross-lane gate on lane-bit MK_ (xor-shuffle); lo lane uses row g0,
// hi lane uses row g1 with columns swapped so "mine" coeff comes first
#define SG(n) { float pr_ = __shfl_xor(cr##n, MK_, 64);                       \
                float pi_ = __shfl_xor(ci##n, MK_, 64);                       \
                float xr_ = cr##n, xi_ = ci##n;                               \
                cr##n = A_ * xr_ - B_ * xi_ + C_ * pr_ - D_ * pi_;            \
                ci##n = A_ * xi_ + B_ * xr_ + C_ * pi_ + D_ * pr_; }
#define SHFL_GATE(mask, g0, g1) {                                             \
    const int MK_ = (mask);                                                   \
    const bool hi_ = (t & (mask)) != 0;                                       \
    const float A_ = hi_ ? g1.z : g0.x;                                       \
    const float B_ = hi_ ? g1.w : g0.y;                                       \
    const float C_ = hi_ ? g1.x : g0.z;                                       \
    const float D_ = hi_ ? g1.y : g0.w;                                       \
    FORALL16(SG) }

// encoding factor pair per qubit, Pt-bit selection folded in
#define MKF(q) { float xv_ = xb[q];                                           \
    float ex_ = __expf(2.0f * xv_);                                           \
    float h_ = (1.0f - 2.0f / (ex_ + 1.0f)) * (PI_F * 0.5f);                  \
    float s_ = __sinf(h_), c_ = __cosf(h_);                                   \
    bool bt_ = (Pt >> (9 - q)) & 1;                                           \
    f0_##q = bt_ ? s_ : c_;                                                   \
    f1_##q = bt_ ? c_ : s_; }

// layer-0 amplitudes: P(j) for j<16 only touches qubits {0,1,6,7,8,9};
// amp = base(b0) * F6(b3)*F7(b2^b3)*F8(b1^b2)*F9(b0^b1)
#define INIT_AMP(J) {                                                         \
    constexpr int j_ = (J);                                                   \
    cr##J = ((j_ & 1) ? u1_ : u0_)                                            \
          * (((j_ >> 3) & 1) ? f1_6 : f0_6)                                   \
          * ((((j_ >> 2) ^ (j_ >> 3)) & 1) ? f1_7 : f0_7)                     \
          * ((((j_ >> 1) ^ (j_ >> 2)) & 1) ? f1_8 : f0_8)                     \
          * (((j_ ^ (j_ >> 1)) & 1) ? f1_9 : f0_9);                           \
    ci##J = 0.0f; }

// phase-A gather with ring permutation fused (pj_ is a compile-time constant)
#define GAT(n) { constexpr int pj_ = cnot_chain_ce(n);                        \
    const int pk_ = Pt ^ pj_;                                                 \
    float2 v_ = st[e][pk_ + (pk_ >> 5)];                                      \
    cr##n = v_.x; ci##n = v_.y; }

#define STA(n) st[e][baseA + n] = make_float2(cr##n, ci##n);
#define RDB(n) { float2 v_ = st[e][n * 66 + boff]; cr##n = v_.x; ci##n = v_.y; }
#define WRB(n) st[e][n * 66 + boff] = make_float2(cr##n, ci##n);

#define RED(n) { float p_ = cr##n * cr##n + ci##n * ci##n; S_ += p_;          \
    w0 += (((n) >> 3) & 1) ? -p_ : p_;                                        \
    w1 += (((n) >> 2) & 1) ? -p_ : p_;                                        \
    w2 += (((n) >> 1) & 1) ? -p_ : p_;                                        \
    w3 += ((n) & 1) ? -p_ : p_; }

#define WRED(v) { v += __shfl_xor(v, 1, 64);  v += __shfl_xor(v, 2, 64);      \
                  v += __shfl_xor(v, 4, 64);  v += __shfl_xor(v, 8, 64);      \
                  v += __shfl_xor(v, 16, 64); v += __shfl_xor(v, 32, 64); }

// ---- prep: fused M = Rz(c)*Ry(b)*Rx(a) per (layer,qubit) -> global scratch.
// Wave-uniform data; main kernel s_loads it straight into SGPRs.
__global__ void vq_prep(const float* __restrict__ w, float4* __restrict__ mats) {
    const int tid = threadIdx.x;
    if (tid < NL * NQ) {
        const float* wp = w + tid * 3;
        float sa = __sinf(wp[0] * 0.5f), ca = __cosf(wp[0] * 0.5f);
        float sb = __sinf(wp[1] * 0.5f), cb = __cosf(wp[1] * 0.5f);
        float sc = __sinf(wp[2] * 0.5f), cc = __cosf(wp[2] * 0.5f);
        float c00r = cb * ca,  c00i =  sa * sb;
        float c01r = -sb * ca, c01i = -cb * sa;
        float c10r =  sb * ca, c10i = -cb * sa;
        float c11r =  cb * ca, c11i = -sb * sa;
        float4 m0, m1;
        m0.x = cc * c00r + sc * c00i;  m0.y = cc * c00i - sc * c00r;
        m0.z = cc * c01r + sc * c01i;  m0.w = cc * c01i - sc * c01r;
        m1.x = cc * c10r - sc * c10i;  m1.y = cc * c10i + sc * c10r;
        m1.z = cc * c11r - sc * c11i;  m1.w = cc * c11i + sc * c11r;
        mats[tid * 2] = m0;
        mats[tid * 2 + 1] = m1;
    }
}

__global__ __launch_bounds__(TPB)
void vq_main(const float* __restrict__ x, const float4* __restrict__ mats,
             float* __restrict__ out) {
    __shared__ float2 st[EPB][CSLOTS];

    const int tid = threadIdx.x;
    const int e = tid >> 6;        // batch sub-element (one wave each)
    const int t = tid & 63;        // lane within element
    const int b = blockIdx.x * EPB + e;

    // P(t<<4): lane bit m is k-bit 4+m (phase A: k = t*16 + j)
    int Pt = 0;
#pragma unroll
    for (int m = 0; m < 6; ++m)
        Pt ^= ((t >> m) & 1) ? cnot_chain_ce(1 << (4 + m)) : 0;

    // wave-uniform x row -> scalar loads
    const int bu = __builtin_amdgcn_readfirstlane(b);
    const float* xb = x + bu * NQ;

    FORALLQ(DECL_F)
    FORALLQ(MKF)

    FORALL16(DECL_AMP)
    {
        float com_ = f0_2 * f0_3 * f0_4 * f0_5;
        float u0_ = f0_0 * f0_1 * com_;
        float u1_ = f1_0 * f1_1 * com_;
        FORALL16(INIT_AMP)
    }

#pragma unroll 1
    for (int l = 0; l < NL; ++l) {
        const float4* mp = mats + l * NQ * 2;   // uniform -> s_load
        if (l > 0) {
            FORALL16(GAT)
            __syncthreads();   // all gathers done before phase-A stores
        }
        // phase A: qubits 6..9 on j-bits 3..0 (matrices in SGPRs)
        { float4 g0 = mp[12], g1 = mp[13]; GATE_BIT3(g0, g1) }
        { float4 g0 = mp[14], g1 = mp[15]; GATE_BIT2(g0, g1) }
        { float4 g0 = mp[16], g1 = mp[17]; GATE_BIT1(g0, g1) }
        { float4 g0 = mp[18], g1 = mp[19]; GATE_BIT0(g0, g1) }
        // qubits 4,5 on lane bits 1,0 (k bits 5,4)
        { float4 g0 = mp[8],  g1 = mp[9];  SHFL_GATE(2, g0, g1) }
        { float4 g0 = mp[10], g1 = mp[11]; SHFL_GATE(1, g0, g1) }
        // store phase-A layout: k = t*16+j -> slot k + (k>>5)
        {
            const int baseA = t * 16 + (t >> 1);
            FORALL16(STA)
        }
        __syncthreads();
        // phase B: amp i holds k = i*64 + t
        {
            const int boff = t + (t >> 5);
            FORALL16(RDB)
        }
        { float4 g0 = mp[0], g1 = mp[1]; GATE_BIT3(g0, g1) }
        { float4 g0 = mp[2], g1 = mp[3]; GATE_BIT2(g0, g1) }
        { float4 g0 = mp[4], g1 = mp[5]; GATE_BIT1(g0, g1) }
        { float4 g0 = mp[6], g1 = mp[7]; GATE_BIT0(g0, g1) }
        if (l < NL - 1) {
            const int boff = t + (t >> 5);
            FORALL16(WRB)      // same slots this lane just read -> no barrier first
            __syncthreads();
        }
    }

    // ---- readout from phase-B registers: k = i*64 + t
    float S_ = 0.0f, w0 = 0.0f, w1 = 0.0f, w2 = 0.0f, w3 = 0.0f;
    FORALL16(RED)
    float w4 = ((t >> 5) & 1) ? -S_ : S_;
    float w5 = ((t >> 4) & 1) ? -S_ : S_;
    float w6 = ((t >> 3) & 1) ? -S_ : S_;
    float w7 = ((t >> 2) & 1) ? -S_ : S_;
    float w8 = ((t >> 1) & 1) ? -S_ : S_;
    float w9 = (t & 1) ? -S_ : S_;

    WRED(w0) WRED(w1) WRED(w2) WRED(w3) WRED(w4)
    WRED(w5) WRED(w6) WRED(w7) WRED(w8) WRED(w9)

    if (t == 0) {
        float* op = out + b * NQ;
        op[0] = w0; op[1] = w1; op[2] = w2; op[3] = w3; op[4] = w4;
        op[5] = w5; op[6] = w6; op[7] = w7; op[8] = w8; op[9] = w9;
    }
}

extern "C" void kernel_launch(void* const* d_in, const int* in_sizes, int n_in,
                              void* d_out, int out_size, void* d_ws, size_t ws_size,
                              hipStream_t stream) {
    const float* x = (const float*)d_in[0];   // (16384, 10) fp32
    const float* w = (const float*)d_in[1];   // (3, 10, 3) fp32
    float* out = (float*)d_out;               // (16384, 10) fp32
    float4* mats = (float4*)d_ws;             // 30 * 2 * float4 = 960 B scratch
    const int B = in_sizes[0] / NQ;           // 16384
    vq_prep<<<dim3(1), dim3(64), 0, stream>>>(w, mats);
    vq_main<<<dim3(B / EPB), dim3(TPB), 0, stream>>>(x, mats, out);
}

// Round 6
// 164.704 us; speedup vs baseline: 1.4041x; 1.3067x over previous
//
#include <hip/hip_runtime.h>
#include <math.h>

#define NQ 10
#define NL 3
#define PI_F 3.14159265358979f
#define TPB 64         // one wave per block; wave handles TWO batch elements
#define IIOFF 1088     // im-plane offset (v2f slots); 1088*8 = 8704 B imm offset

// packed pair: lane-local (element_a, element_b)
typedef float v2f __attribute__((ext_vector_type(2)));
__device__ __forceinline__ v2f sp2(float s) { v2f r; r.x = s; r.y = s; return r; }
__device__ __forceinline__ v2f shflx2(v2f v, int m) {
    v2f r; r.x = __shfl_xor(v.x, m, 64); r.y = __shfl_xor(v.y, m, 64); return r;
}

// Composed CNOT-ring permutation (GF(2)-linear), compile-time only.
__host__ __device__ constexpr int cnot_chain_ce(int j) {
    for (int i = NQ - 1; i >= 0; --i) {
        int tq = (i + 1) % NQ;
        j ^= ((j >> (NQ - 1 - i)) & 1) << (NQ - 1 - tq);
    }
    return j;
}

#define FORALL16(F) F(0) F(1) F(2) F(3) F(4) F(5) F(6) F(7) \
                    F(8) F(9) F(10) F(11) F(12) F(13) F(14) F(15)

#define DECL_AMP(n) v2f cr##n, ci##n;

// 2x2 complex gate on a register pair; coefficients a0..d1 are v2f splats of
// SGPR scalars -> v_pk_fma_f32 with broadcast. Defined against fixed names.
#define GP(p0, p1) {                                                          \
    v2f s0r_ = cr##p0, s0i_ = ci##p0, s1r_ = cr##p1, s1i_ = ci##p1;           \
    cr##p0 = a0_ * s0r_ - b0_ * s0i_ + c0_ * s1r_ - d0_ * s1i_;               \
    ci##p0 = a0_ * s0i_ + b0_ * s0r_ + c0_ * s1i_ + d0_ * s1r_;               \
    cr##p1 = a1_ * s0r_ - b1_ * s0i_ + c1_ * s1r_ - d1_ * s1i_;               \
    ci##p1 = a1_ * s0i_ + b1_ * s0r_ + c1_ * s1i_ + d1_ * s1r_; }

#define LOADG(q) const float4 g0_ = mp[2 * (q)], g1_ = mp[2 * (q) + 1];       \
    const v2f a0_ = sp2(g0_.x), b0_ = sp2(g0_.y), c0_ = sp2(g0_.z),           \
              d0_ = sp2(g0_.w), a1_ = sp2(g1_.x), b1_ = sp2(g1_.y),           \
              c1_ = sp2(g1_.z), d1_ = sp2(g1_.w);

#define GATE_BIT3 GP(0,8) GP(1,9) GP(2,10) GP(3,11) GP(4,12) GP(5,13) GP(6,14) GP(7,15)
#define GATE_BIT2 GP(0,4) GP(1,5) GP(2,6) GP(3,7) GP(8,12) GP(9,13) GP(10,14) GP(11,15)
#define GATE_BIT1 GP(0,2) GP(1,3) GP(4,6) GP(5,7) GP(8,10) GP(9,11) GP(12,14) GP(13,15)
#define GATE_BIT0 GP(0,1) GP(2,3) GP(4,5) GP(6,7) GP(8,9) GP(10,11) GP(12,13) GP(14,15)

// cross-lane gate on lane-bit MK_; shuffles ride the DS pipe (swizzle)
#define SG(n) { v2f pr_ = shflx2(cr##n, MK_), pi_ = shflx2(ci##n, MK_);       \
                v2f xr_ = cr##n, xi_ = ci##n;                                 \
                cr##n = A_ * xr_ - B_ * xi_ + C_ * pr_ - D_ * pi_;            \
                ci##n = A_ * xi_ + B_ * xr_ + C_ * pi_ + D_ * pr_; }
#define SHFL_GATE(mask, ga, gb) {                                             \
    const int MK_ = (mask);                                                   \
    const bool hi_ = (t & (mask)) != 0;                                       \
    const v2f A_ = sp2(hi_ ? gb.z : ga.x), B_ = sp2(hi_ ? gb.w : ga.y);       \
    const v2f C_ = sp2(hi_ ? gb.x : ga.z), D_ = sp2(hi_ ? gb.y : ga.w);       \
    FORALL16(SG) }

// encoding factor pair per qubit (both elements packed); Pt-bit select folded
#define MKF(q) {                                                              \
    float e0_ = __expf(2.0f * xa[q]);                                         \
    float h0_ = (1.0f - 2.0f / (e0_ + 1.0f)) * (PI_F * 0.5f);                 \
    float e1_ = __expf(2.0f * xbv[q]);                                        \
    float h1_ = (1.0f - 2.0f / (e1_ + 1.0f)) * (PI_F * 0.5f);                 \
    v2f s_, c_;                                                               \
    s_.x = __sinf(h0_); s_.y = __sinf(h1_);                                   \
    c_.x = __cosf(h0_); c_.y = __cosf(h1_);                                   \
    bool bt_ = (Pt >> (9 - q)) & 1;                                           \
    f0_##q = bt_ ? s_ : c_;                                                   \
    f1_##q = bt_ ? c_ : s_; }

// layer-0 amplitudes: P(j), j<16 touches only qubits {0,1,6,7,8,9}
#define INIT_AMP(J) {                                                         \
    constexpr int j_ = (J);                                                   \
    cr##J = ((j_ & 1) ? u1_ : u0_)                                            \
          * (((j_ >> 3) & 1) ? f1_6 : f0_6)                                   \
          * ((((j_ >> 2) ^ (j_ >> 3)) & 1) ? f1_7 : f0_7)                     \
          * ((((j_ >> 1) ^ (j_ >> 2)) & 1) ? f1_8 : f0_8)                     \
          * (((j_ ^ (j_ >> 1)) & 1) ? f1_9 : f0_9);                           \
    ci##J = sp2(0.0f); }

// phase-A gather with ring permutation fused (pj_ compile-time)
#define GAT(n) { constexpr int pj_ = cnot_chain_ce(n);                        \
    const int pk_ = Pt ^ pj_;                                                 \
    const int sl_ = pk_ + (pk_ >> 4);                                         \
    cr##n = sh[sl_]; ci##n = sh[sl_ + IIOFF]; }

// phase-A store: k = t*16+j -> slot 17t + j
#define STA(n) sh[baseA + n] = cr##n; sh[baseA + n + IIOFF] = ci##n;
// phase-B: amp i holds k = i*64 + t -> slot 68i + boff
#define RDB(n) { cr##n = sh[n * 68 + boff]; ci##n = sh[n * 68 + boff + IIOFF]; }
#define WRB(n) sh[n * 68 + boff] = cr##n; sh[n * 68 + boff + IIOFF] = ci##n;

#define RED(n) { v2f p_ = cr##n * cr##n + ci##n * ci##n; S_ = S_ + p_;        \
    w0 = (((n) >> 3) & 1) ? (w0 - p_) : (w0 + p_);                            \
    w1 = (((n) >> 2) & 1) ? (w1 - p_) : (w1 + p_);                            \
    w2 = (((n) >> 1) & 1) ? (w2 - p_) : (w2 + p_);                            \
    w3 = ((n) & 1) ? (w3 - p_) : (w3 + p_); }

#define WRED(v) { v = v + shflx2(v, 1);  v = v + shflx2(v, 2);                \
                  v = v + shflx2(v, 4);  v = v + shflx2(v, 8);                \
                  v = v + shflx2(v, 16); v = v + shflx2(v, 32); }

// ---- prep: fused M = Rz(c)*Ry(b)*Rx(a) per (layer,qubit) -> global scratch
__global__ void vq_prep(const float* __restrict__ w, float4* __restrict__ mats) {
    const int tid = threadIdx.x;
    if (tid < NL * NQ) {
        const float* wp = w + tid * 3;
        float sa = __sinf(wp[0] * 0.5f), ca = __cosf(wp[0] * 0.5f);
        float sb = __sinf(wp[1] * 0.5f), cb = __cosf(wp[1] * 0.5f);
        float sc = __sinf(wp[2] * 0.5f), cc = __cosf(wp[2] * 0.5f);
        float c00r = cb * ca,  c00i =  sa * sb;
        float c01r = -sb * ca, c01i = -cb * sa;
        float c10r =  sb * ca, c10i = -cb * sa;
        float c11r =  cb * ca, c11i = -sb * sa;
        float4 m0, m1;
        m0.x = cc * c00r + sc * c00i;  m0.y = cc * c00i - sc * c00r;
        m0.z = cc * c01r + sc * c01i;  m0.w = cc * c01i - sc * c01r;
        m1.x = cc * c10r - sc * c10i;  m1.y = cc * c10i + sc * c10r;
        m1.z = cc * c11r - sc * c11i;  m1.w = cc * c11i + sc * c11r;
        mats[tid * 2] = m0;
        mats[tid * 2 + 1] = m1;
    }
}

__global__ __launch_bounds__(TPB)
void vq_main(const float* __restrict__ x, const float4* __restrict__ mats,
             float* __restrict__ out) {
    __shared__ v2f sh[2 * IIOFF];   // re-plane [0,1088) + im-plane [1088,2176)

    const int t = threadIdx.x;            // lane (one wave per block)
    const int b0 = blockIdx.x * 2;        // element a
    const int b1 = b0 + 1;                // element b

    // P(t<<4): lane bit m is k-bit 4+m (phase A: k = t*16 + j)
    int Pt = 0;
#pragma unroll
    for (int m = 0; m < 6; ++m)
        Pt ^= ((t >> m) & 1) ? cnot_chain_ce(1 << (4 + m)) : 0;

    const float* xa = x + b0 * NQ;    // uniform rows -> s_load
    const float* xbv = x + b1 * NQ;

    v2f f0_0, f1_0, f0_1, f1_1, f0_6, f1_6, f0_7, f1_7, f0_8, f1_8, f0_9, f1_9;
    v2f u0_, u1_;
    {
        // qubits 2..5: P(j)-bit is 0 for all j<16 -> only f0 needed
        v2f com_ = sp2(1.0f);
        v2f f0_2, f1_2, f0_3, f1_3, f0_4, f1_4, f0_5, f1_5;
        MKF(2) MKF(3) MKF(4) MKF(5)
        com_ = f0_2 * f0_3 * f0_4 * f0_5;
        MKF(0) MKF(1)
        u0_ = f0_0 * f0_1 * com_;
        u1_ = f1_0 * f1_1 * com_;
        MKF(6) MKF(7) MKF(8) MKF(9)
    }

    FORALL16(DECL_AMP)
    FORALL16(INIT_AMP)

#pragma unroll 1
    for (int l = 0; l < NL; ++l) {
        const float4* mp = mats + l * NQ * 2;   // uniform -> s_load
        if (l > 0) {
            FORALL16(GAT)
            __syncthreads();   // gathers done before phase-A stores
        }
        // phase A: qubits 6..9 on j-bits 3..0 (coeffs SGPR, splat to both halves)
        { LOADG(6) GATE_BIT3 }
        { LOADG(7) GATE_BIT2 }
        { LOADG(8) GATE_BIT1 }
        { LOADG(9) GATE_BIT0 }
        // qubits 4,5 on lane bits 1,0 (k bits 5,4)
        { const float4 ga = mp[8],  gb = mp[9];  SHFL_GATE(2, ga, gb) }
        { const float4 ga = mp[10], gb = mp[11]; SHFL_GATE(1, ga, gb) }
        {
            const int baseA = 17 * t;
            FORALL16(STA)
        }
        __syncthreads();
        {
            const int boff = t + (t >> 4);
            FORALL16(RDB)
        }
        // phase B: qubits 0..3 on i-bits 3..0
        { LOADG(0) GATE_BIT3 }
        { LOADG(1) GATE_BIT2 }
        { LOADG(2) GATE_BIT1 }
        { LOADG(3) GATE_BIT0 }
        if (l < NL - 1) {
            const int boff = t + (t >> 4);
            FORALL16(WRB)      // same slots this lane just read
            __syncthreads();
        }
    }

    // ---- readout from phase-B registers: k = i*64 + t (both elements packed)
    v2f S_ = sp2(0.0f), w0 = sp2(0.0f), w1 = sp2(0.0f), w2 = sp2(0.0f), w3 = sp2(0.0f);
    FORALL16(RED)
    v2f w4 = ((t >> 5) & 1) ? -S_ : S_;
    v2f w5 = ((t >> 4) & 1) ? -S_ : S_;
    v2f w6 = ((t >> 3) & 1) ? -S_ : S_;
    v2f w7 = ((t >> 2) & 1) ? -S_ : S_;
    v2f w8 = ((t >> 1) & 1) ? -S_ : S_;
    v2f w9 = (t & 1) ? -S_ : S_;

    WRED(w0) WRED(w1) WRED(w2) WRED(w3) WRED(w4)
    WRED(w5) WRED(w6) WRED(w7) WRED(w8) WRED(w9)

    if (t == 0) {
        float* oa = out + b0 * NQ;
        float* ob = out + b1 * NQ;
        oa[0] = w0.x; oa[1] = w1.x; oa[2] = w2.x; oa[3] = w3.x; oa[4] = w4.x;
        oa[5] = w5.x; oa[6] = w6.x; oa[7] = w7.x; oa[8] = w8.x; oa[9] = w9.x;
        ob[0] = w0.y; ob[1] = w1.y; ob[2] = w2.y; ob[3] = w3.y; ob[4] = w4.y;
        ob[5] = w5.y; ob[6] = w6.y; ob[7] = w7.y; ob[8] = w8.y; ob[9] = w9.y;
    }
}

extern "C" void kernel_launch(void* const* d_in, const int* in_sizes, int n_in,
                              void* d_out, int out_size, void* d_ws, size_t ws_size,
                              hipStream_t stream) {
    const float* x = (const float*)d_in[0];   // (16384, 10) fp32
    const float* w = (const float*)d_in[1];   // (3, 10, 3) fp32
    float* out = (float*)d_out;               // (16384, 10) fp32
    float4* mats = (float4*)d_ws;             // 30 * 2 * float4 = 960 B scratch
    const int B = in_sizes[0] / NQ;           // 16384
    vq_prep<<<dim3(1), dim3(64), 0, stream>>>(w, mats);
    vq_main<<<dim3(B / 2), dim3(TPB), 0, stream>>>(x, mats, out);
}

// Round 7
// 152.893 us; speedup vs baseline: 1.5125x; 1.0772x over previous
//
#include <hip/hip_runtime.h>
#include <math.h>

#define NQ 10
#define NL 3
#define PI_F 3.14159265358979f
#define TPB 64         // one wave per block; wave handles TWO batch elements
#define NSLOT 1088     // one plane (re or im) of 1024 v2f amps + pad, 8704 B

// packed pair: lane-local (element_a, element_b)
typedef float v2f __attribute__((ext_vector_type(2)));
__device__ __forceinline__ v2f sp2(float s) { v2f r; r.x = s; r.y = s; return r; }

// lane-xor exchange routed to the cheapest pipe per mask:
// 1,2 -> DPP quad_perm (VALU); 4,8,16 -> ds_swizzle; 32 -> shfl (ds_permute)
template<int MASK>
__device__ __forceinline__ float lxor1(float v) {
    if constexpr (MASK == 1)        // quad_perm [1,0,3,2] = 0xB1
        return __int_as_float(__builtin_amdgcn_update_dpp(
            0, __float_as_int(v), 0xB1, 0xF, 0xF, true));
    else if constexpr (MASK == 2)   // quad_perm [2,3,0,1] = 0x4E
        return __int_as_float(__builtin_amdgcn_update_dpp(
            0, __float_as_int(v), 0x4E, 0xF, 0xF, true));
    else if constexpr (MASK <= 16)  // BitMode swizzle: xor<<10 | and 0x1F
        return __int_as_float(__builtin_amdgcn_ds_swizzle(
            __float_as_int(v), (MASK << 10) | 0x1F));
    else
        return __shfl_xor(v, MASK, 64);
}
template<int MASK>
__device__ __forceinline__ v2f lxor2(v2f v) {
    v2f r; r.x = lxor1<MASK>(v.x); r.y = lxor1<MASK>(v.y); return r;
}

// Composed CNOT-ring permutation (GF(2)-linear), compile-time only.
__host__ __device__ constexpr int cnot_chain_ce(int j) {
    for (int i = NQ - 1; i >= 0; --i) {
        int tq = (i + 1) % NQ;
        j ^= ((j >> (NQ - 1 - i)) & 1) << (NQ - 1 - tq);
    }
    return j;
}

#define FORALL16(F) F(0) F(1) F(2) F(3) F(4) F(5) F(6) F(7) \
                    F(8) F(9) F(10) F(11) F(12) F(13) F(14) F(15)

#define DECL_AMP(n) v2f cr##n, ci##n;

// 2x2 complex gate on a register pair; coeffs splat from SGPR scalars
#define GP(p0, p1) {                                                          \
    v2f s0r_ = cr##p0, s0i_ = ci##p0, s1r_ = cr##p1, s1i_ = ci##p1;           \
    cr##p0 = a0_ * s0r_ - b0_ * s0i_ + c0_ * s1r_ - d0_ * s1i_;               \
    ci##p0 = a0_ * s0i_ + b0_ * s0r_ + c0_ * s1i_ + d0_ * s1r_;               \
    cr##p1 = a1_ * s0r_ - b1_ * s0i_ + c1_ * s1r_ - d1_ * s1i_;               \
    ci##p1 = a1_ * s0i_ + b1_ * s0r_ + c1_ * s1i_ + d1_ * s1r_; }

#define LOADG(q) const float4 g0_ = mp[2 * (q)], g1_ = mp[2 * (q) + 1];       \
    const v2f a0_ = sp2(g0_.x), b0_ = sp2(g0_.y), c0_ = sp2(g0_.z),           \
              d0_ = sp2(g0_.w), a1_ = sp2(g1_.x), b1_ = sp2(g1_.y),           \
              c1_ = sp2(g1_.z), d1_ = sp2(g1_.w);

#define GATE_BIT3 GP(0,8) GP(1,9) GP(2,10) GP(3,11) GP(4,12) GP(5,13) GP(6,14) GP(7,15)
#define GATE_BIT2 GP(0,4) GP(1,5) GP(2,6) GP(3,7) GP(8,12) GP(9,13) GP(10,14) GP(11,15)
#define GATE_BIT1 GP(0,2) GP(1,3) GP(4,6) GP(5,7) GP(8,10) GP(9,11) GP(12,14) GP(13,15)
#define GATE_BIT0 GP(0,1) GP(2,3) GP(4,5) GP(6,7) GP(8,9) GP(10,11) GP(12,13) GP(14,15)

// cross-lane gate on lane-bit MK_; lo lane row g0, hi lane row g1 cols swapped
#define SG(n) { v2f pr_ = lxor2<MK_>(cr##n), pi_ = lxor2<MK_>(ci##n);         \
                v2f xr_ = cr##n, xi_ = ci##n;                                 \
                cr##n = A_ * xr_ - B_ * xi_ + C_ * pr_ - D_ * pi_;            \
                ci##n = A_ * xi_ + B_ * xr_ + C_ * pi_ + D_ * pr_; }
#define SHFL_GATE(MASK, q) {                                                  \
    constexpr int MK_ = (MASK);                                               \
    const float4 ga_ = mp[2 * (q)], gb_ = mp[2 * (q) + 1];                    \
    const bool hi_ = (t & MK_) != 0;                                          \
    const v2f A_ = sp2(hi_ ? gb_.z : ga_.x), B_ = sp2(hi_ ? gb_.w : ga_.y);   \
    const v2f C_ = sp2(hi_ ? gb_.x : ga_.z), D_ = sp2(hi_ ? gb_.y : ga_.w);   \
    FORALL16(SG) }

// encoding factor pair per qubit (both elements packed); Pt-bit select folded
#define MKF(q) {                                                              \
    float e0_ = __expf(2.0f * xa[q]);                                         \
    float h0_ = (1.0f - 2.0f / (e0_ + 1.0f)) * (PI_F * 0.5f);                 \
    float e1_ = __expf(2.0f * xbv[q]);                                        \
    float h1_ = (1.0f - 2.0f / (e1_ + 1.0f)) * (PI_F * 0.5f);                 \
    v2f s_, c_;                                                               \
    s_.x = __sinf(h0_); s_.y = __sinf(h1_);                                   \
    c_.x = __cosf(h0_); c_.y = __cosf(h1_);                                   \
    bool bt_ = (Pt >> (9 - q)) & 1;                                           \
    f0_##q = bt_ ? s_ : c_;                                                   \
    f1_##q = bt_ ? c_ : s_; }

// layer-0 amplitudes at P(k), perm fused; j<16 touches only qubits {0,1,6,7,8,9}
#define INIT_AMP(J) {                                                         \
    constexpr int j_ = (J);                                                   \
    cr##J = ((j_ & 1) ? u1_ : u0_)                                            \
          * (((j_ >> 3) & 1) ? f1_6 : f0_6)                                   \
          * ((((j_ >> 2) ^ (j_ >> 3)) & 1) ? f1_7 : f0_7)                     \
          * ((((j_ >> 1) ^ (j_ >> 2)) & 1) ? f1_8 : f0_8)                     \
          * (((j_ ^ (j_ >> 1)) & 1) ? f1_9 : f0_9);                           \
    ci##J = sp2(0.0f); }

// permutation via LDS, one plane at a time; slot(k) = k + (k>>4)
#define STRE(n) sh[baseA + n] = cr##n;
#define GRE(n)  { constexpr int pj_ = cnot_chain_ce(n);                       \
                  const int pk_ = Pt ^ pj_;                                   \
                  cr##n = sh[pk_ + (pk_ >> 4)]; }
#define STIM(n) sh[baseA + n] = ci##n;
#define GIM(n)  { constexpr int pj_ = cnot_chain_ce(n);                       \
                  const int pk_ = Pt ^ pj_;                                   \
                  ci##n = sh[pk_ + (pk_ >> 4)]; }

// readout: k = t*16 + j; qubits 6..9 live in j bits 3..0
#define RED(n) { v2f p_ = cr##n * cr##n + ci##n * ci##n; S_ = S_ + p_;        \
    w6 = (((n) >> 3) & 1) ? (w6 - p_) : (w6 + p_);                            \
    w7 = (((n) >> 2) & 1) ? (w7 - p_) : (w7 + p_);                            \
    w8 = (((n) >> 1) & 1) ? (w8 - p_) : (w8 + p_);                            \
    w9 = ((n) & 1) ? (w9 - p_) : (w9 + p_); }

#define WRED(v) { v.x += __shfl_xor(v.x, 1, 64);  v.y += __shfl_xor(v.y, 1, 64);  \
                  v.x += __shfl_xor(v.x, 2, 64);  v.y += __shfl_xor(v.y, 2, 64);  \
                  v.x += __shfl_xor(v.x, 4, 64);  v.y += __shfl_xor(v.y, 4, 64);  \
                  v.x += __shfl_xor(v.x, 8, 64);  v.y += __shfl_xor(v.y, 8, 64);  \
                  v.x += __shfl_xor(v.x, 16, 64); v.y += __shfl_xor(v.y, 16, 64); \
                  v.x += __shfl_xor(v.x, 32, 64); v.y += __shfl_xor(v.y, 32, 64); }

// ---- prep: fused M = Rz(c)*Ry(b)*Rx(a) per (layer,qubit) -> global scratch
__global__ void vq_prep(const float* __restrict__ w, float4* __restrict__ mats) {
    const int tid = threadIdx.x;
    if (tid < NL * NQ) {
        const float* wp = w + tid * 3;
        float sa = __sinf(wp[0] * 0.5f), ca = __cosf(wp[0] * 0.5f);
        float sb = __sinf(wp[1] * 0.5f), cb = __cosf(wp[1] * 0.5f);
        float sc = __sinf(wp[2] * 0.5f), cc = __cosf(wp[2] * 0.5f);
        float c00r = cb * ca,  c00i =  sa * sb;
        float c01r = -sb * ca, c01i = -cb * sa;
        float c10r =  sb * ca, c10i = -cb * sa;
        float c11r =  cb * ca, c11i = -sb * sa;
        float4 m0, m1;
        m0.x = cc * c00r + sc * c00i;  m0.y = cc * c00i - sc * c00r;
        m0.z = cc * c01r + sc * c01i;  m0.w = cc * c01i - sc * c01r;
        m1.x = cc * c10r - sc * c10i;  m1.y = cc * c10i + sc * c10r;
        m1.z = cc * c11r - sc * c11i;  m1.w = cc * c11i + sc * c11r;
        mats[tid * 2] = m0;
        mats[tid * 2 + 1] = m1;
    }
}

__global__ __launch_bounds__(TPB)
void vq_main(const float* __restrict__ x, const float4* __restrict__ mats,
             float* __restrict__ out) {
    __shared__ v2f sh[NSLOT];   // single re-or-im plane, reused

    const int t = threadIdx.x;            // lane (one wave per block)
    const int b0 = blockIdx.x * 2;        // element a
    const int b1 = b0 + 1;                // element b

    // P(t<<4): lane bit m is k-bit 4+m (layout k = t*16 + j, all layers)
    int Pt = 0;
#pragma unroll
    for (int m = 0; m < 6; ++m)
        Pt ^= ((t >> m) & 1) ? cnot_chain_ce(1 << (4 + m)) : 0;

    const float* xa = x + b0 * NQ;    // uniform rows -> s_load
    const float* xbv = x + b1 * NQ;

    v2f f0_0, f1_0, f0_1, f1_1, f0_6, f1_6, f0_7, f1_7, f0_8, f1_8, f0_9, f1_9;
    v2f u0_, u1_;
    {
        // qubits 2..5: P(j)-bit is 0 for all j<16 -> only f0 needed
        v2f f0_2, f1_2, f0_3, f1_3, f0_4, f1_4, f0_5, f1_5;
        MKF(2) MKF(3) MKF(4) MKF(5)
        v2f com_ = f0_2 * f0_3 * f0_4 * f0_5;
        MKF(0) MKF(1)
        u0_ = f0_0 * f0_1 * com_;
        u1_ = f1_0 * f1_1 * com_;
        MKF(6) MKF(7) MKF(8) MKF(9)
    }

    FORALL16(DECL_AMP)
    FORALL16(INIT_AMP)

#pragma unroll 1
    for (int l = 0; l < NL; ++l) {
        const float4* mp = mats + l * NQ * 2;   // uniform -> s_load
        if (l > 0) {
            // CNOT-ring permutation via LDS, re plane then im plane
            const int baseA = 17 * t;           // slot(t*16+j) = 17t + j
            FORALL16(STRE)
            __syncthreads();
            FORALL16(GRE)
            __syncthreads();
            FORALL16(STIM)
            __syncthreads();
            FORALL16(GIM)
            __syncthreads();
        }
        // register gates: qubits 6..9 on j-bits 3..0
        { LOADG(6) GATE_BIT3 }
        { LOADG(7) GATE_BIT2 }
        { LOADG(8) GATE_BIT1 }
        { LOADG(9) GATE_BIT0 }
        // lane gates: qubit q on lane bit (5-q)
        SHFL_GATE(32, 0)
        SHFL_GATE(16, 1)
        SHFL_GATE(8, 2)
        SHFL_GATE(4, 3)
        SHFL_GATE(2, 4)
        SHFL_GATE(1, 5)
    }

    // ---- readout: k = t*16 + j (both elements packed)
    v2f S_ = sp2(0.0f), w6 = sp2(0.0f), w7 = sp2(0.0f), w8 = sp2(0.0f), w9 = sp2(0.0f);
    FORALL16(RED)
    v2f w0 = ((t >> 5) & 1) ? -S_ : S_;
    v2f w1 = ((t >> 4) & 1) ? -S_ : S_;
    v2f w2 = ((t >> 3) & 1) ? -S_ : S_;
    v2f w3 = ((t >> 2) & 1) ? -S_ : S_;
    v2f w4 = ((t >> 1) & 1) ? -S_ : S_;
    v2f w5 = (t & 1) ? -S_ : S_;

    WRED(w0) WRED(w1) WRED(w2) WRED(w3) WRED(w4)
    WRED(w5) WRED(w6) WRED(w7) WRED(w8) WRED(w9)

    if (t == 0) {
        float* oa = out + b0 * NQ;
        float* ob = out + b1 * NQ;
        oa[0] = w0.x; oa[1] = w1.x; oa[2] = w2.x; oa[3] = w3.x; oa[4] = w4.x;
        oa[5] = w5.x; oa[6] = w6.x; oa[7] = w7.x; oa[8] = w8.x; oa[9] = w9.x;
        ob[0] = w0.y; ob[1] = w1.y; ob[2] = w2.y; ob[3] = w3.y; ob[4] = w4.y;
        ob[5] = w5.y; ob[6] = w6.y; ob[7] = w7.y; ob[8] = w8.y; ob[9] = w9.y;
    }
}

extern "C" void kernel_launch(void* const* d_in, const int* in_sizes, int n_in,
                              void* d_out, int out_size, void* d_ws, size_t ws_size,
                              hipStream_t stream) {
    const float* x = (const float*)d_in[0];   // (16384, 10) fp32
    const float* w = (const float*)d_in[1];   // (3, 10, 3) fp32
    float* out = (float*)d_out;               // (16384, 10) fp32
    float4* mats = (float4*)d_ws;             // 30 * 2 * float4 = 960 B scratch
    const int B = in_sizes[0] / NQ;           // 16384
    vq_prep<<<dim3(1), dim3(64), 0, stream>>>(w, mats);
    vq_main<<<dim3(B / 2), dim3(TPB), 0, stream>>>(x, mats, out);
}

// Round 8
// 152.635 us; speedup vs baseline: 1.5151x; 1.0017x over previous
//
#include <hip/hip_runtime.h>
#include <math.h>

#define NQ 10
#define NL 3
#define PI_F 3.14159265358979f
#define TPB 256        // 4 waves/block; each wave: 2 batch elements, private LDS plane
#define NSLOT 1088     // one plane of 1024 v2f amps + pad (slot = k + (k>>4))

// packed pair: lane-local (element_a, element_b)
typedef float v2f __attribute__((ext_vector_type(2)));
__device__ __forceinline__ v2f sp2(float s) { v2f r; r.x = s; r.y = s; return r; }

// ---- guaranteed VOP3P packed-fp32 (the compiler was scalarizing v2f math)
__device__ __forceinline__ v2f pk_mul_v(v2f a, v2f b) {
    v2f d; asm("v_pk_mul_f32 %0, %1, %2" : "=v"(d) : "v"(a), "v"(b)); return d;
}
__device__ __forceinline__ v2f pk_fma_v(v2f a, v2f b, v2f c) {   // a*b + c
    v2f d; asm("v_pk_fma_f32 %0, %1, %2, %3" : "=v"(d) : "v"(a), "v"(b), "v"(c));
    return d;
}
__device__ __forceinline__ v2f pk_fms_v(v2f a, v2f b, v2f c) {   // c - a*b
    v2f d; asm("v_pk_fma_f32 %0, %1, %2, %3 neg_lo:[1,0,0] neg_hi:[1,0,0]"
               : "=v"(d) : "v"(a), "v"(b), "v"(c));
    return d;
}

// lane-xor exchange routed to the cheapest pipe per mask:
// 1,2 -> DPP quad_perm (VALU); 4,8,16 -> ds_swizzle; 32 -> shfl (ds_permute)
template<int MASK>
__device__ __forceinline__ float lxor1(float v) {
    if constexpr (MASK == 1)        // quad_perm [1,0,3,2] = 0xB1
        return __int_as_float(__builtin_amdgcn_update_dpp(
            0, __float_as_int(v), 0xB1, 0xF, 0xF, true));
    else if constexpr (MASK == 2)   // quad_perm [2,3,0,1] = 0x4E
        return __int_as_float(__builtin_amdgcn_update_dpp(
            0, __float_as_int(v), 0x4E, 0xF, 0xF, true));
    else if constexpr (MASK <= 16)  // BitMode swizzle: xor<<10 | and 0x1F
        return __int_as_float(__builtin_amdgcn_ds_swizzle(
            __float_as_int(v), (MASK << 10) | 0x1F));
    else
        return __shfl_xor(v, MASK, 64);
}
template<int MASK>
__device__ __forceinline__ v2f lxor2(v2f v) {
    v2f r; r.x = lxor1<MASK>(v.x); r.y = lxor1<MASK>(v.y); return r;
}

// Composed CNOT-ring permutation (GF(2)-linear), compile-time only.
__host__ __device__ constexpr int cnot_chain_ce(int j) {
    for (int i = NQ - 1; i >= 0; --i) {
        int tq = (i + 1) % NQ;
        j ^= ((j >> (NQ - 1 - i)) & 1) << (NQ - 1 - tq);
    }
    return j;
}

#define FORALL16(F) F(0) F(1) F(2) F(3) F(4) F(5) F(6) F(7) \
                    F(8) F(9) F(10) F(11) F(12) F(13) F(14) F(15)

#define DECL_AMP(n) v2f cr##n, ci##n;

// 2x2 complex gate on a register pair, all packed ops.
// row0: cr' = A0*s0r - B0*s0i + C0*s1r - D0*s1i ; ci' = A0*s0i + B0*s0r + C0*s1i + D0*s1r
#define GP(p0, p1) {                                                          \
    v2f tr_ = cr##p0, ti_ = ci##p0, sr_ = cr##p1, si_ = ci##p1;               \
    v2f t0_ = pk_mul_v(tr_, A0_); t0_ = pk_fms_v(B0_, ti_, t0_);              \
    t0_ = pk_fma_v(C0_, sr_, t0_); t0_ = pk_fms_v(D0_, si_, t0_);             \
    v2f t1_ = pk_mul_v(ti_, A0_); t1_ = pk_fma_v(B0_, tr_, t1_);              \
    t1_ = pk_fma_v(C0_, si_, t1_); t1_ = pk_fma_v(D0_, sr_, t1_);             \
    v2f t2_ = pk_mul_v(tr_, A1_); t2_ = pk_fms_v(B1_, ti_, t2_);              \
    t2_ = pk_fma_v(C1_, sr_, t2_); t2_ = pk_fms_v(D1_, si_, t2_);             \
    v2f t3_ = pk_mul_v(ti_, A1_); t3_ = pk_fma_v(B1_, tr_, t3_);              \
    t3_ = pk_fma_v(C1_, si_, t3_); t3_ = pk_fma_v(D1_, sr_, t3_);             \
    cr##p0 = t0_; ci##p0 = t1_; cr##p1 = t2_; ci##p1 = t3_; }

#define LOADG(q) const float4 g0_ = mp[2 * (q)], g1_ = mp[2 * (q) + 1];       \
    const v2f A0_ = sp2(g0_.x), B0_ = sp2(g0_.y), C0_ = sp2(g0_.z),           \
              D0_ = sp2(g0_.w), A1_ = sp2(g1_.x), B1_ = sp2(g1_.y),           \
              C1_ = sp2(g1_.z), D1_ = sp2(g1_.w);

#define GATE_BIT3 GP(0,8) GP(1,9) GP(2,10) GP(3,11) GP(4,12) GP(5,13) GP(6,14) GP(7,15)
#define GATE_BIT2 GP(0,4) GP(1,5) GP(2,6) GP(3,7) GP(8,12) GP(9,13) GP(10,14) GP(11,15)
#define GATE_BIT1 GP(0,2) GP(1,3) GP(4,6) GP(5,7) GP(8,10) GP(9,11) GP(12,14) GP(13,15)
#define GATE_BIT0 GP(0,1) GP(2,3) GP(4,5) GP(6,7) GP(8,9) GP(10,11) GP(12,13) GP(14,15)

// cross-lane gate on lane-bit MK_; lo lane row g0, hi lane row g1 cols swapped
#define SG(n) { v2f pr_ = lxor2<MK_>(cr##n), pi_ = lxor2<MK_>(ci##n);         \
    v2f xr_ = cr##n, xi_ = ci##n;                                             \
    v2f u_ = pk_mul_v(xr_, A_); u_ = pk_fms_v(B_, xi_, u_);                   \
    u_ = pk_fma_v(C_, pr_, u_); u_ = pk_fms_v(D_, pi_, u_);                   \
    v2f v_ = pk_mul_v(xi_, A_); v_ = pk_fma_v(B_, xr_, v_);                   \
    v_ = pk_fma_v(C_, pi_, v_); v_ = pk_fma_v(D_, pr_, v_);                   \
    cr##n = u_; ci##n = v_; }
#define SHFL_GATE(MASK, q) {                                                  \
    constexpr int MK_ = (MASK);                                               \
    const float4 ga_ = mp[2 * (q)], gb_ = mp[2 * (q) + 1];                    \
    const bool hi_ = (t & MK_) != 0;                                          \
    const v2f A_ = sp2(hi_ ? gb_.z : ga_.x), B_ = sp2(hi_ ? gb_.w : ga_.y);   \
    const v2f C_ = sp2(hi_ ? gb_.x : ga_.z), D_ = sp2(hi_ ? gb_.y : ga_.w);   \
    FORALL16(SG) }

// encoding factor pair per qubit (both elements packed); Pt-bit select folded
#define MKF(q) {                                                              \
    float e0_ = __expf(2.0f * xa[q]);                                         \
    float h0_ = (1.0f - 2.0f / (e0_ + 1.0f)) * (PI_F * 0.5f);                 \
    float e1_ = __expf(2.0f * xbv[q]);                                        \
    float h1_ = (1.0f - 2.0f / (e1_ + 1.0f)) * (PI_F * 0.5f);                 \
    v2f s_, c_;                                                               \
    s_.x = __sinf(h0_); s_.y = __sinf(h1_);                                   \
    c_.x = __cosf(h0_); c_.y = __cosf(h1_);                                   \
    bool bt_ = (Pt >> (9 - q)) & 1;                                           \
    f0_##q = bt_ ? s_ : c_;                                                   \
    f1_##q = bt_ ? c_ : s_; }

// layer-0 amplitudes at P(k), perm fused; j<16 touches only qubits {0,1,6,7,8,9}
#define INIT_AMP(J) {                                                         \
    constexpr int j_ = (J);                                                   \
    cr##J = ((j_ & 1) ? u1_ : u0_)                                            \
          * (((j_ >> 3) & 1) ? f1_6 : f0_6)                                   \
          * ((((j_ >> 2) ^ (j_ >> 3)) & 1) ? f1_7 : f0_7)                     \
          * ((((j_ >> 1) ^ (j_ >> 2)) & 1) ? f1_8 : f0_8)                     \
          * (((j_ ^ (j_ >> 1)) & 1) ? f1_9 : f0_9);                           \
    ci##J = sp2(0.0f); }

// permutation via LDS, one plane at a time; slot(k) = k + (k>>4)
#define STRE(n) shp[baseA + n] = cr##n;
#define GRE(n)  { constexpr int pj_ = cnot_chain_ce(n);                       \
                  const int pk_ = Pt ^ pj_;                                   \
                  cr##n = shp[pk_ + (pk_ >> 4)]; }
#define STIM(n) shp[baseA + n] = ci##n;
#define GIM(n)  { constexpr int pj_ = cnot_chain_ce(n);                       \
                  const int pk_ = Pt ^ pj_;                                   \
                  ci##n = shp[pk_ + (pk_ >> 4)]; }

// readout: k = t*16 + j; qubits 6..9 live in j bits 3..0
#define RED(n) { v2f p_ = pk_fma_v(cr##n, cr##n, pk_mul_v(ci##n, ci##n));     \
    S_ = S_ + p_;                                                             \
    w6 = (((n) >> 3) & 1) ? (w6 - p_) : (w6 + p_);                            \
    w7 = (((n) >> 2) & 1) ? (w7 - p_) : (w7 + p_);                            \
    w8 = (((n) >> 1) & 1) ? (w8 - p_) : (w8 + p_);                            \
    w9 = ((n) & 1) ? (w9 - p_) : (w9 + p_); }

#define WR1(v, M) { v.x += lxor1<M>(v.x); v.y += lxor1<M>(v.y); }
#define WRED(v) { WR1(v, 1) WR1(v, 2) WR1(v, 4) WR1(v, 8) WR1(v, 16) WR1(v, 32) }

// ---- prep: fused M = Rz(c)*Ry(b)*Rx(a) per (layer,qubit) -> global scratch
__global__ void vq_prep(const float* __restrict__ w, float4* __restrict__ mats) {
    const int tid = threadIdx.x;
    if (tid < NL * NQ) {
        const float* wp = w + tid * 3;
        float sa = __sinf(wp[0] * 0.5f), ca = __cosf(wp[0] * 0.5f);
        float sb = __sinf(wp[1] * 0.5f), cb = __cosf(wp[1] * 0.5f);
        float sc = __sinf(wp[2] * 0.5f), cc = __cosf(wp[2] * 0.5f);
        float c00r = cb * ca,  c00i =  sa * sb;
        float c01r = -sb * ca, c01i = -cb * sa;
        float c10r =  sb * ca, c10i = -cb * sa;
        float c11r =  cb * ca, c11i = -sb * sa;
        float4 m0, m1;
        m0.x = cc * c00r + sc * c00i;  m0.y = cc * c00i - sc * c00r;
        m0.z = cc * c01r + sc * c01i;  m0.w = cc * c01i - sc * c01r;
        m1.x = cc * c10r - sc * c10i;  m1.y = cc * c10i + sc * c10r;
        m1.z = cc * c11r - sc * c11i;  m1.w = cc * c11i + sc * c11r;
        mats[tid * 2] = m0;
        mats[tid * 2 + 1] = m1;
    }
}

__global__ __launch_bounds__(TPB)
__attribute__((amdgpu_waves_per_eu(4, 4)))
void vq_main(const float* __restrict__ x, const float4* __restrict__ mats,
             float* __restrict__ out) {
    __shared__ v2f sh[4][NSLOT];   // one plane per wave

    const int tid = threadIdx.x;
    const int wv = tid >> 6;              // wave in block
    const int t = tid & 63;               // lane
    v2f* shp = sh[wv];
    const int b0 = (blockIdx.x * 4 + wv) * 2;   // element a
    const int b1 = b0 + 1;                      // element b

    // P(t<<4): lane bit m is k-bit 4+m (layout k = t*16 + j, all layers)
    int Pt = 0;
#pragma unroll
    for (int m = 0; m < 6; ++m)
        Pt ^= ((t >> m) & 1) ? cnot_chain_ce(1 << (4 + m)) : 0;

    const float* xa = x + b0 * NQ;    // wave-uniform rows -> s_load
    const float* xbv = x + b1 * NQ;

    v2f f0_0, f1_0, f0_1, f1_1, f0_6, f1_6, f0_7, f1_7, f0_8, f1_8, f0_9, f1_9;
    v2f u0_, u1_;
    {
        // qubits 2..5: P(j)-bit is 0 for all j<16 -> only f0 needed
        v2f f0_2, f1_2, f0_3, f1_3, f0_4, f1_4, f0_5, f1_5;
        MKF(2) MKF(3) MKF(4) MKF(5)
        v2f com_ = f0_2 * f0_3 * f0_4 * f0_5;
        MKF(0) MKF(1)
        u0_ = f0_0 * f0_1 * com_;
        u1_ = f1_0 * f1_1 * com_;
        MKF(6) MKF(7) MKF(8) MKF(9)
    }

    FORALL16(DECL_AMP)
    FORALL16(INIT_AMP)

#pragma unroll 1
    for (int l = 0; l < NL; ++l) {
        const float4* mp = mats + l * NQ * 2;   // uniform -> s_load
        if (l > 0) {
            // CNOT-ring permutation via LDS, re plane then im plane
            const int baseA = 17 * t;           // slot(t*16+j) = 17t + j
            FORALL16(STRE)
            __syncthreads();
            FORALL16(GRE)
            __syncthreads();
            FORALL16(STIM)
            __syncthreads();
            FORALL16(GIM)
            __syncthreads();
        }
        // register gates: qubits 6..9 on j-bits 3..0 (packed VOP3P math)
        { LOADG(6) GATE_BIT3 }
        { LOADG(7) GATE_BIT2 }
        { LOADG(8) GATE_BIT1 }
        { LOADG(9) GATE_BIT0 }
        // lane gates: qubit q on lane bit (5-q)
        SHFL_GATE(32, 0)
        SHFL_GATE(16, 1)
        SHFL_GATE(8, 2)
        SHFL_GATE(4, 3)
        SHFL_GATE(2, 4)
        SHFL_GATE(1, 5)
    }

    // ---- readout: k = t*16 + j (both elements packed)
    v2f S_ = sp2(0.0f), w6 = sp2(0.0f), w7 = sp2(0.0f), w8 = sp2(0.0f), w9 = sp2(0.0f);
    FORALL16(RED)
    v2f w0 = ((t >> 5) & 1) ? -S_ : S_;
    v2f w1 = ((t >> 4) & 1) ? -S_ : S_;
    v2f w2 = ((t >> 3) & 1) ? -S_ : S_;
    v2f w3 = ((t >> 2) & 1) ? -S_ : S_;
    v2f w4 = ((t >> 1) & 1) ? -S_ : S_;
    v2f w5 = (t & 1) ? -S_ : S_;

    WRED(w0) WRED(w1) WRED(w2) WRED(w3) WRED(w4)
    WRED(w5) WRED(w6) WRED(w7) WRED(w8) WRED(w9)

    if (t == 0) {
        float* oa = out + b0 * NQ;
        float* ob = out + b1 * NQ;
        oa[0] = w0.x; oa[1] = w1.x; oa[2] = w2.x; oa[3] = w3.x; oa[4] = w4.x;
        oa[5] = w5.x; oa[6] = w6.x; oa[7] = w7.x; oa[8] = w8.x; oa[9] = w9.x;
        ob[0] = w0.y; ob[1] = w1.y; ob[2] = w2.y; ob[3] = w3.y; ob[4] = w4.y;
        ob[5] = w5.y; ob[6] = w6.y; ob[7] = w7.y; ob[8] = w8.y; ob[9] = w9.y;
    }
}

extern "C" void kernel_launch(void* const* d_in, const int* in_sizes, int n_in,
                              void* d_out, int out_size, void* d_ws, size_t ws_size,
                              hipStream_t stream) {
    const float* x = (const float*)d_in[0];   // (16384, 10) fp32
    const float* w = (const float*)d_in[1];   // (3, 10, 3) fp32
    float* out = (float*)d_out;               // (16384, 10) fp32
    float4* mats = (float4*)d_ws;             // 30 * 2 * float4 = 960 B scratch
    const int B = in_sizes[0] / NQ;           // 16384
    vq_prep<<<dim3(1), dim3(64), 0, stream>>>(w, mats);
    vq_main<<<dim3(B / 8), dim3(TPB), 0, stream>>>(x, mats, out);
}

// Round 9
// 136.720 us; speedup vs baseline: 1.6915x; 1.1164x over previous
//
#include <hip/hip_runtime.h>
#include <math.h>

#define NQ 10
#define NL 3
#define PI_F 3.14159265358979f
#define TPB 256        // 4 waves/block; each wave: 2 batch elements in f16 halves

typedef _Float16 h2 __attribute__((ext_vector_type(2)));   // (elem_a, elem_b)
typedef float v2f __attribute__((ext_vector_type(2)));     // init-path fp32 pair

__device__ __forceinline__ unsigned bcu(h2 v) { return __builtin_bit_cast(unsigned, v); }
__device__ __forceinline__ h2 bch(unsigned u) { return __builtin_bit_cast(h2, u); }
__device__ __forceinline__ unsigned duph(float f) { h2 h; h.x = (_Float16)f; h.y = h.x; return bcu(h); }
__device__ __forceinline__ h2 zh2() { h2 h; h.x = (_Float16)0.0f; h.y = h.x; return h; }

// v_pk_*_f16: one instr = 2 f16 FMA/lane (both elements) — true 2x over f32 rate
__device__ __forceinline__ h2 pk_mul(h2 a, h2 b) {
    h2 d; asm("v_pk_mul_f16 %0, %1, %2" : "=v"(d) : "v"(a), "v"(b)); return d;
}
__device__ __forceinline__ h2 pk_fma(h2 a, h2 b, h2 c) {   // a*b + c
    h2 d; asm("v_pk_fma_f16 %0, %1, %2, %3" : "=v"(d) : "v"(a), "v"(b), "v"(c)); return d;
}
__device__ __forceinline__ h2 pk_fms(h2 a, h2 b, h2 c) {   // c - a*b
    h2 d; asm("v_pk_fma_f16 %0, %1, %2, %3 neg_lo:[1,0,0] neg_hi:[1,0,0]"
              : "=v"(d) : "v"(a), "v"(b), "v"(c)); return d;
}

// lane-xor exchange, cheapest pipe per mask: 1,2 DPP; 4 = xor3(quad_perm)∘xor7;
// 8 = xor7∘xor15 (all DPP/VALU); 16 ds_swizzle; 32 bpermute
template<int MASK>
__device__ __forceinline__ unsigned lxu(unsigned v) {
    if constexpr (MASK == 1)
        return (unsigned)__builtin_amdgcn_update_dpp(0, (int)v, 0xB1, 0xF, 0xF, true);
    else if constexpr (MASK == 2)
        return (unsigned)__builtin_amdgcn_update_dpp(0, (int)v, 0x4E, 0xF, 0xF, true);
    else if constexpr (MASK == 4) {
        int a = __builtin_amdgcn_update_dpp(0, (int)v, 0x1B, 0xF, 0xF, true);    // xor3
        return (unsigned)__builtin_amdgcn_update_dpp(0, a, 0x141, 0xF, 0xF, true); // ∘xor7
    } else if constexpr (MASK == 8) {
        int a = __builtin_amdgcn_update_dpp(0, (int)v, 0x141, 0xF, 0xF, true);   // xor7
        return (unsigned)__builtin_amdgcn_update_dpp(0, a, 0x140, 0xF, 0xF, true); // ∘xor15
    } else if constexpr (MASK == 16)
        return (unsigned)__builtin_amdgcn_ds_swizzle((int)v, 0x401F);            // xor16
    else
        return (unsigned)__shfl_xor((int)v, 32, 64);
}

// Composed CNOT-ring permutation (GF(2)-linear), compile-time only.
__host__ __device__ constexpr int cnot_chain_ce(int j) {
    for (int i = NQ - 1; i >= 0; --i) {
        int tq = (i + 1) % NQ;
        j ^= ((j >> (NQ - 1 - i)) & 1) << (NQ - 1 - tq);
    }
    return j;
}

#define FORALL16(F) F(0) F(1) F(2) F(3) F(4) F(5) F(6) F(7) \
                    F(8) F(9) F(10) F(11) F(12) F(13) F(14) F(15)

#define DECL_AMP(n) h2 cr##n, ci##n;

// 2x2 complex gate on a register pair (coeffs A0_..D1_ are h2 duplicated pairs)
#define GP(p0, p1) {                                                          \
    h2 s0r_ = cr##p0, s0i_ = ci##p0, s1r_ = cr##p1, s1i_ = ci##p1;            \
    h2 t0_ = pk_mul(A0_, s0r_); t0_ = pk_fms(B0_, s0i_, t0_);                 \
    t0_ = pk_fma(C0_, s1r_, t0_); t0_ = pk_fms(D0_, s1i_, t0_);               \
    h2 t1_ = pk_mul(A0_, s0i_); t1_ = pk_fma(B0_, s0r_, t1_);                 \
    t1_ = pk_fma(C0_, s1i_, t1_); t1_ = pk_fma(D0_, s1r_, t1_);               \
    h2 t2_ = pk_mul(A1_, s0r_); t2_ = pk_fms(B1_, s0i_, t2_);                 \
    t2_ = pk_fma(C1_, s1r_, t2_); t2_ = pk_fms(D1_, s1i_, t2_);               \
    h2 t3_ = pk_mul(A1_, s0i_); t3_ = pk_fma(B1_, s0r_, t3_);                 \
    t3_ = pk_fma(C1_, s1i_, t3_); t3_ = pk_fma(D1_, s1r_, t3_);               \
    cr##p0 = t0_; ci##p0 = t1_; cr##p1 = t2_; ci##p1 = t3_; }

#define LOADG(q) const uint4 g0_ = mq[2 * (q)], g1_ = mq[2 * (q) + 1];        \
    const h2 A0_ = bch(g0_.x), B0_ = bch(g0_.y), C0_ = bch(g0_.z),            \
             D0_ = bch(g0_.w), A1_ = bch(g1_.x), B1_ = bch(g1_.y),            \
             C1_ = bch(g1_.z), D1_ = bch(g1_.w);

#define GATE_BIT3 GP(0,8) GP(1,9) GP(2,10) GP(3,11) GP(4,12) GP(5,13) GP(6,14) GP(7,15)
#define GATE_BIT2 GP(0,4) GP(1,5) GP(2,6) GP(3,7) GP(8,12) GP(9,13) GP(10,14) GP(11,15)
#define GATE_BIT1 GP(0,2) GP(1,3) GP(4,6) GP(5,7) GP(8,10) GP(9,11) GP(12,14) GP(13,15)
#define GATE_BIT0 GP(0,1) GP(2,3) GP(4,5) GP(6,7) GP(8,9) GP(10,11) GP(12,13) GP(14,15)

// cross-lane gate on lane-bit MK_; lo lane row m0, hi lane row m1 cols swapped
#define SG(n) { h2 pr_ = bch(lxu<MK_>(bcu(cr##n))), pi_ = bch(lxu<MK_>(bcu(ci##n))); \
    h2 xr_ = cr##n, xi_ = ci##n;                                              \
    h2 u_ = pk_mul(A_, xr_); u_ = pk_fms(B_, xi_, u_);                        \
    u_ = pk_fma(C_, pr_, u_); u_ = pk_fms(D_, pi_, u_);                       \
    h2 v_ = pk_mul(A_, xi_); v_ = pk_fma(B_, xr_, v_);                        \
    v_ = pk_fma(C_, pi_, v_); v_ = pk_fma(D_, pr_, v_);                       \
    cr##n = u_; ci##n = v_; }
#define SHFL_GATE(MASK, q) {                                                  \
    constexpr int MK_ = (MASK);                                               \
    const uint4 u0_ = mq[2 * (q)], u1_ = mq[2 * (q) + 1];                     \
    const bool hi_ = (t & MK_) != 0;                                          \
    const h2 A_ = bch(hi_ ? u1_.z : u0_.x), B_ = bch(hi_ ? u1_.w : u0_.y);    \
    const h2 C_ = bch(hi_ ? u1_.x : u0_.z), D_ = bch(hi_ ? u1_.y : u0_.w);    \
    FORALL16(SG) }

// encoding factor pair per qubit (fp32, both elements); Pt-bit select folded
#define MKF(q) {                                                              \
    float e0_ = __expf(2.0f * xa[q]);                                         \
    float h0_ = (1.0f - 2.0f / (e0_ + 1.0f)) * (PI_F * 0.5f);                 \
    float e1_ = __expf(2.0f * xbv[q]);                                        \
    float h1_ = (1.0f - 2.0f / (e1_ + 1.0f)) * (PI_F * 0.5f);                 \
    v2f s_, c_;                                                               \
    s_.x = __sinf(h0_); s_.y = __sinf(h1_);                                   \
    c_.x = __cosf(h0_); c_.y = __cosf(h1_);                                   \
    bool bt_ = (Pt >> (9 - q)) & 1;                                           \
    f0_##q = bt_ ? s_ : c_;                                                   \
    f1_##q = bt_ ? c_ : s_; }

// layer-0 amplitudes at P(k) (perm fused), fp32 product -> one f16 pack
#define INIT_AMP(J) {                                                         \
    constexpr int j_ = (J);                                                   \
    v2f r_ = ((j_ & 1) ? u1_ : u0_)                                           \
          * (((j_ >> 3) & 1) ? f1_6 : f0_6)                                   \
          * ((((j_ >> 2) ^ (j_ >> 3)) & 1) ? f1_7 : f0_7)                     \
          * ((((j_ >> 1) ^ (j_ >> 2)) & 1) ? f1_8 : f0_8)                     \
          * (((j_ ^ (j_ >> 1)) & 1) ? f1_9 : f0_9);                           \
    h2 h_; h_.x = (_Float16)r_.x; h_.y = (_Float16)r_.y;                      \
    cr##J = h_; ci##J = zh2(); }

// CNOT-ring permutation via wave-private LDS plane, re+im packed in one b64.
// Same-wave DS ops complete in order -> no __syncthreads needed.
#define STP(n) stq[base8 + n] = make_uint2(bcu(cr##n), bcu(ci##n));
#define GAT(n) { constexpr int pj_ = cnot_chain_ce(n);                        \
    const int pk_ = Pt ^ pj_;                                                 \
    uint2 v_ = stq[pk_ + (pk_ >> 4)];                                         \
    cr##n = bch(v_.x); ci##n = bch(v_.y); }

// readout: k = t*16 + j; qubits 6..9 in j(reg) bits 3..0 (fp32 accumulate)
#define RED(n) {                                                              \
    float ra_ = (float)cr##n.x, rb_ = (float)cr##n.y;                         \
    float ia_ = (float)ci##n.x, ib_ = (float)ci##n.y;                         \
    float pa_ = ra_ * ra_ + ia_ * ia_;                                        \
    float pb_ = rb_ * rb_ + ib_ * ib_;                                        \
    Sa_ += pa_; Sb_ += pb_;                                                   \
    w6a += (((n) >> 3) & 1) ? -pa_ : pa_;  w6b += (((n) >> 3) & 1) ? -pb_ : pb_; \
    w7a += (((n) >> 2) & 1) ? -pa_ : pa_;  w7b += (((n) >> 2) & 1) ? -pb_ : pb_; \
    w8a += (((n) >> 1) & 1) ? -pa_ : pa_;  w8b += (((n) >> 1) & 1) ? -pb_ : pb_; \
    w9a += ((n) & 1) ? -pa_ : pa_;         w9b += ((n) & 1) ? -pb_ : pb_; }

#define WR1(v, M) v += __builtin_bit_cast(float, lxu<M>(__builtin_bit_cast(unsigned, v)));
#define WRED(v) { WR1(v, 1) WR1(v, 2) WR1(v, 4) WR1(v, 8) WR1(v, 16) WR1(v, 32) }

__global__ __launch_bounds__(TPB)
__attribute__((amdgpu_waves_per_eu(4, 4)))
void vq_main(const float* __restrict__ x, const float* __restrict__ w,
             float* __restrict__ out) {
    __shared__ uint2 stw[4][1088];                 // wave-private perm planes
    __shared__ __align__(16) unsigned msh[NL * NQ * 8];   // 30 gates x 8 f16-pair coeffs

    const int tid = threadIdx.x;
    const int wv = tid >> 6;
    const int t = tid & 63;
    uint2* stq = stw[wv];
    const int b0 = (blockIdx.x * 4 + wv) * 2;
    const int b1 = b0 + 1;

    // ---- in-block prep: fused M = Rz*Ry*Rx per (layer,qubit), f16-pair coeffs
    if (tid < NL * NQ) {
        const float* wp = w + tid * 3;
        float sa = __sinf(wp[0] * 0.5f), ca = __cosf(wp[0] * 0.5f);
        float sb = __sinf(wp[1] * 0.5f), cb = __cosf(wp[1] * 0.5f);
        float sc = __sinf(wp[2] * 0.5f), cc = __cosf(wp[2] * 0.5f);
        float c00r = cb * ca,  c00i =  sa * sb;
        float c01r = -sb * ca, c01i = -cb * sa;
        float c10r =  sb * ca, c10i = -cb * sa;
        float c11r =  cb * ca, c11i = -sb * sa;
        unsigned* mg = msh + tid * 8;
        mg[0] = duph(cc * c00r + sc * c00i);  mg[1] = duph(cc * c00i - sc * c00r);
        mg[2] = duph(cc * c01r + sc * c01i);  mg[3] = duph(cc * c01i - sc * c01r);
        mg[4] = duph(cc * c10r - sc * c10i);  mg[5] = duph(cc * c10i + sc * c10r);
        mg[6] = duph(cc * c11r - sc * c11i);  mg[7] = duph(cc * c11i + sc * c11r);
    }

    // P(t<<4): lane bit m is k-bit 4+m (layout k = t*16 + j, all layers)
    int Pt = 0;
#pragma unroll
    for (int m = 0; m < 6; ++m)
        Pt ^= ((t >> m) & 1) ? cnot_chain_ce(1 << (4 + m)) : 0;

    const float* xa = x + b0 * NQ;
    const float* xbv = x + b1 * NQ;

    v2f f0_0, f1_0, f0_1, f1_1, f0_6, f1_6, f0_7, f1_7, f0_8, f1_8, f0_9, f1_9;
    v2f u0_, u1_;
    {
        // qubits 2..5: P(j)-bit is 0 for all j<16 -> only f0 needed
        v2f f0_2, f1_2, f0_3, f1_3, f0_4, f1_4, f0_5, f1_5;
        MKF(2) MKF(3) MKF(4) MKF(5)
        v2f com_ = f0_2 * f0_3 * f0_4 * f0_5;
        MKF(0) MKF(1)
        u0_ = f0_0 * f0_1 * com_;
        u1_ = f1_0 * f1_1 * com_;
        MKF(6) MKF(7) MKF(8) MKF(9)
    }

    FORALL16(DECL_AMP)
    FORALL16(INIT_AMP)

    __syncthreads();   // msh ready (only cross-wave dependency in the kernel)

#pragma unroll 1
    for (int l = 0; l < NL; ++l) {
        const uint4* mq = ((const uint4*)msh) + l * NQ * 2;
        if (l > 0) {
            const int base8 = 17 * t;           // slot(t*16+j) = 17t + j
            FORALL16(STP)
            __builtin_amdgcn_wave_barrier();    // pin st->ld order (HW is in-order)
            FORALL16(GAT)
        }
        // register gates: qubits 6..9 on j-bits 3..0 (pk f16 math)
        { LOADG(6) GATE_BIT3 }
        { LOADG(7) GATE_BIT2 }
        { LOADG(8) GATE_BIT1 }
        { LOADG(9) GATE_BIT0 }
        // lane gates: qubit q on lane bit (5-q)
        SHFL_GATE(32, 0)
        SHFL_GATE(16, 1)
        SHFL_GATE(8, 2)
        SHFL_GATE(4, 3)
        SHFL_GATE(2, 4)
        SHFL_GATE(1, 5)
    }

    // ---- readout (fp32): k = t*16 + j
    float Sa_ = 0.0f, Sb_ = 0.0f;
    float w6a = 0.0f, w7a = 0.0f, w8a = 0.0f, w9a = 0.0f;
    float w6b = 0.0f, w7b = 0.0f, w8b = 0.0f, w9b = 0.0f;
    FORALL16(RED)
    float w0a = ((t >> 5) & 1) ? -Sa_ : Sa_,  w0b = ((t >> 5) & 1) ? -Sb_ : Sb_;
    float w1a = ((t >> 4) & 1) ? -Sa_ : Sa_,  w1b = ((t >> 4) & 1) ? -Sb_ : Sb_;
    float w2a = ((t >> 3) & 1) ? -Sa_ : Sa_,  w2b = ((t >> 3) & 1) ? -Sb_ : Sb_;
    float w3a = ((t >> 2) & 1) ? -Sa_ : Sa_,  w3b = ((t >> 2) & 1) ? -Sb_ : Sb_;
    float w4a = ((t >> 1) & 1) ? -Sa_ : Sa_,  w4b = ((t >> 1) & 1) ? -Sb_ : Sb_;
    float w5a = (t & 1) ? -Sa_ : Sa_,         w5b = (t & 1) ? -Sb_ : Sb_;

    WRED(w0a) WRED(w1a) WRED(w2a) WRED(w3a) WRED(w4a)
    WRED(w5a) WRED(w6a) WRED(w7a) WRED(w8a) WRED(w9a)
    WRED(w0b) WRED(w1b) WRED(w2b) WRED(w3b) WRED(w4b)
    WRED(w5b) WRED(w6b) WRED(w7b) WRED(w8b) WRED(w9b)

    if (t == 0) {
        float* oa = out + b0 * NQ;
        float* ob = out + b1 * NQ;
        oa[0] = w0a; oa[1] = w1a; oa[2] = w2a; oa[3] = w3a; oa[4] = w4a;
        oa[5] = w5a; oa[6] = w6a; oa[7] = w7a; oa[8] = w8a; oa[9] = w9a;
        ob[0] = w0b; ob[1] = w1b; ob[2] = w2b; ob[3] = w3b; ob[4] = w4b;
        ob[5] = w5b; ob[6] = w6b; ob[7] = w7b; ob[8] = w8b; ob[9] = w9b;
    }
}

extern "C" void kernel_launch(void* const* d_in, const int* in_sizes, int n_in,
                              void* d_out, int out_size, void* d_ws, size_t ws_size,
                              hipStream_t stream) {
    const float* x = (const float*)d_in[0];   // (16384, 10) fp32
    const float* w = (const float*)d_in[1];   // (3, 10, 3) fp32
    float* out = (float*)d_out;               // (16384, 10) fp32
    const int B = in_sizes[0] / NQ;           // 16384
    vq_main<<<dim3(B / 8), dim3(TPB), 0, stream>>>(x, w, out);
}

// Round 10
// 104.925 us; speedup vs baseline: 2.2040x; 1.3030x over previous
//
#include <hip/hip_runtime.h>
#include <math.h>

#define NQ 10
#define NL 3
#define PI_F 3.14159265358979f
#define TPB 256   // 4 waves/block; ONE batch element per wave

typedef _Float16 f16x8 __attribute__((ext_vector_type(8)));
typedef _Float16 h2t  __attribute__((ext_vector_type(2)));
typedef float    f32x4 __attribute__((ext_vector_type(4)));

// Composed CNOT-ring permutation (GF(2)-linear), compile-time only.
__host__ __device__ constexpr int cnot_chain_ce(int j) {
    for (int i = NQ - 1; i >= 0; --i) {
        int tq = (i + 1) % NQ;
        j ^= ((j >> (NQ - 1 - i)) & 1) << (NQ - 1 - tq);
    }
    return j;
}

__device__ __forceinline__ unsigned pkh(float r, float i) {
    return __builtin_bit_cast(unsigned, __builtin_amdgcn_cvt_pkrtz(r, i));
}

// Build a B-fragment (f16x8): element e (=2d+h) = selected f16 half of dw[e].
// psel picks lo halves (re-plane lanes) or hi halves (im-plane lanes).
__device__ __forceinline__ f16x8 mkfrag(unsigned d0, unsigned d1, unsigned d2,
                                        unsigned d3, unsigned d4, unsigned d5,
                                        unsigned d6, unsigned d7, unsigned sel) {
    uint4 u;
    u.x = __builtin_amdgcn_perm(d1, d0, sel);   // high-dword arg, low-dword arg
    u.y = __builtin_amdgcn_perm(d3, d2, sel);
    u.z = __builtin_amdgcn_perm(d5, d4, sel);
    u.w = __builtin_amdgcn_perm(d7, d6, sel);
    return __builtin_bit_cast(f16x8, u);
}

// lane-xor exchange for the final reduction (verified R9): 1,2,4,8 DPP; 16 swizzle; 32 shfl
template<int MASK>
__device__ __forceinline__ unsigned lxu(unsigned v) {
    if constexpr (MASK == 1)
        return (unsigned)__builtin_amdgcn_update_dpp(0, (int)v, 0xB1, 0xF, 0xF, true);
    else if constexpr (MASK == 2)
        return (unsigned)__builtin_amdgcn_update_dpp(0, (int)v, 0x4E, 0xF, 0xF, true);
    else if constexpr (MASK == 4) {
        int a = __builtin_amdgcn_update_dpp(0, (int)v, 0x1B, 0xF, 0xF, true);
        return (unsigned)__builtin_amdgcn_update_dpp(0, a, 0x141, 0xF, 0xF, true);
    } else if constexpr (MASK == 8) {
        int a = __builtin_amdgcn_update_dpp(0, (int)v, 0x141, 0xF, 0xF, true);
        return (unsigned)__builtin_amdgcn_update_dpp(0, a, 0x140, 0xF, 0xF, true);
    } else if constexpr (MASK == 16)
        return (unsigned)__builtin_amdgcn_ds_swizzle((int)v, 0x401F);
    else
        return (unsigned)__shfl_xor((int)v, 32, 64);
}
#define WR1(v, M) v += __builtin_bit_cast(float, lxu<M>(__builtin_bit_cast(unsigned, v)));
#define WRED(v) { WR1(v,1) WR1(v,2) WR1(v,4) WR1(v,8) WR1(v,16) WR1(v,32) }

#define FORALL16(F) F(0) F(1) F(2) F(3) F(4) F(5) F(6) F(7) \
                    F(8) F(9) F(10) F(11) F(12) F(13) F(14) F(15)
#define FORALLQ(F) F(0) F(1) F(2) F(3) F(4) F(5) F(6) F(7) F(8) F(9)

// ============ prep: fused gate matrices -> MFMA A-fragments in d_ws ============
// Per (layer, stage, variant): A is 16x32 f16. stage0: U16 = M6(x)M7(x)M8(x)M9 on j
// (qubit 6 on j-bit3 ... qubit 9 on j-bit0); stage1: M2(x)M3(x)M4(x)M5 on t_lo.
// variant0 (->Sr'): [Ur | -Ui]; variant1 (->Si'): [Ui | Ur].
// A-fragment lane map: m = lane&15, k = (lane>>4)*8 + elem, elem = 2d+h.
__global__ void vq_prep(const float* __restrict__ w, uint4* __restrict__ frag,
                        float* __restrict__ qcoef) {
    __shared__ float msh[NL * NQ][8];
    const int tid = threadIdx.x;
    if (tid < NL * NQ) {
        const float* wp = w + tid * 3;
        float sa = __sinf(wp[0]*0.5f), ca = __cosf(wp[0]*0.5f);
        float sb = __sinf(wp[1]*0.5f), cb = __cosf(wp[1]*0.5f);
        float sc = __sinf(wp[2]*0.5f), cc = __cosf(wp[2]*0.5f);
        float c00r = cb*ca,  c00i =  sa*sb;
        float c01r = -sb*ca, c01i = -cb*sa;
        float c10r =  sb*ca, c10i = -cb*sa;
        float c11r =  cb*ca, c11i = -sb*sa;
        float m[8];
        m[0] = cc*c00r + sc*c00i;  m[1] = cc*c00i - sc*c00r;   // m00
        m[2] = cc*c01r + sc*c01i;  m[3] = cc*c01i - sc*c01r;   // m01
        m[4] = cc*c10r - sc*c10i;  m[5] = cc*c10i + sc*c10r;   // m10
        m[6] = cc*c11r - sc*c11i;  m[7] = cc*c11i + sc*c11r;   // m11
#pragma unroll
        for (int j = 0; j < 8; ++j) msh[tid][j] = m[j];
        const int l = tid / NQ, q = tid % NQ;
        if (q < 2)   // qubit 0/1 gates stay scalar f32 in the main kernel
#pragma unroll
            for (int j = 0; j < 8; ++j) qcoef[(l*2 + q)*8 + j] = m[j];
    }
    __syncthreads();
    const int lane = tid & 63, wg = tid >> 6;
    const int mrow = lane & 15, quad = lane >> 4;
#pragma unroll 1
    for (int c = 0; c < 3; ++c) {
        const int id = c*4 + wg;            // id = l*4 + s*2 + v
        const int l = id >> 2, s = (id >> 1) & 1, v = id & 1;
        const int qb = s ? 2 : 6;
        unsigned pd[4];
#pragma unroll
        for (int d = 0; d < 4; ++d) {
            float hv[2];
#pragma unroll
            for (int h = 0; h < 2; ++h) {
                const int k = quad*8 + 2*d + h;
                const int col = k & 15;
                float er = 1.f, ei = 0.f;   // complex U[mrow][col] = prod of 4 gate entries
#pragma unroll
                for (int p = 0; p < 4; ++p) {
                    const float* mm = msh[l*NQ + qb + p];
                    const int rb = (mrow >> (3-p)) & 1, cb2 = (col >> (3-p)) & 1;
                    const float gr = mm[(rb*2 + cb2)*2], gi = mm[(rb*2 + cb2)*2 + 1];
                    const float nr = er*gr - ei*gi, ni = er*gi + ei*gr;
                    er = nr; ei = ni;
                }
                hv[h] = (k < 16) ? (v ? ei : er) : (v ? er : -ei);
            }
            h2t hh; hh.x = (_Float16)hv[0]; hh.y = (_Float16)hv[1];
            pd[d] = __builtin_bit_cast(unsigned, hh);
        }
        frag[id*64 + lane] = make_uint4(pd[0], pd[1], pd[2], pd[3]);
    }
}

// ============ main kernel ============
// State: wave-private LDS plane, packed (re,im) f16 per amp, slot = k + (k>>4).
// k = t*16 + j (t 6 bits, j 4 bits). Stage A cols: t = b*16 + n (n=lane&15).
// Stage B cols: j' = lane&15, block b = t_hi. B rows: (quad&1)*8+i; plane = quad>>1.

#define DECLF(q) float f0_##q, f1_##q;
#define MKF(q) { float e_ = __expf(2.0f * xr[q]); \
    float h_ = (1.0f - 2.0f / (e_ + 1.0f)) * (PI_F * 0.5f); \
    f1_##q = __sinf(h_); f0_##q = __cosf(h_); }

#define IST(J) { float a_ = pr \
    * ((((J) >> 3) & 1) ? f1_6 : f0_6) * ((((J) >> 2) & 1) ? f1_7 : f0_7) \
    * ((((J) >> 1) & 1) ? f1_8 : f0_8) * (((J) & 1) ? f1_9 : f0_9); \
    P[17*lane + (J)] = pkh(a_, 0.0f); }

#define LDA1(b,i) { constexpr int pc_ = cnot_chain_ce((b)*256) ^ cnot_chain_ce(i); \
    const int pk_ = PBv ^ pc_; dw##i = P[pk_ + (pk_ >> 4)]; }
#define GATH(b) LDA1(b,0) LDA1(b,1) LDA1(b,2) LDA1(b,3) LDA1(b,4) LDA1(b,5) LDA1(b,6) LDA1(b,7) \
    fr##b = mkfrag(dw0,dw1,dw2,dw3,dw4,dw5,dw6,dw7,psel);

#define LDB1(b,i) dw##i = P[sB + 272*(b) + 17*(i)];
#define GATB(b) LDB1(b,0) LDB1(b,1) LDB1(b,2) LDB1(b,3) LDB1(b,4) LDB1(b,5) LDB1(b,6) LDB1(b,7) \
    fr##b = mkfrag(dw0,dw1,dw2,dw3,dw4,dw5,dw6,dw7,psel);

#define MMA_A(b) { \
    f32x4 cr_ = __builtin_amdgcn_mfma_f32_16x16x32_f16(aAr, fr##b, z4, 0, 0, 0); \
    f32x4 ci_ = __builtin_amdgcn_mfma_f32_16x16x32_f16(aAi, fr##b, z4, 0, 0, 0); \
    P[sAst + 272*(b)    ] = pkh(cr_.x, ci_.x); \
    P[sAst + 272*(b) + 1] = pkh(cr_.y, ci_.y); \
    P[sAst + 272*(b) + 2] = pkh(cr_.z, ci_.z); \
    P[sAst + 272*(b) + 3] = pkh(cr_.w, ci_.w); }

#define MMA_B(b) \
    car##b = __builtin_amdgcn_mfma_f32_16x16x32_f16(aBr, fr##b, z4, 0, 0, 0); \
    cai##b = __builtin_amdgcn_mfma_f32_16x16x32_f16(aBi, fr##b, z4, 0, 0, 0);

// complex 2x2 gate on C-accumulator block pair (f32 vectors)
#define CGATE(pa, pb, qp) { \
    const float g0_=(qp)[0], g1_=(qp)[1], g2_=(qp)[2], g3_=(qp)[3]; \
    const float g4_=(qp)[4], g5_=(qp)[5], g6_=(qp)[6], g7_=(qp)[7]; \
    f32x4 ar_ = car##pa, ai_ = cai##pa, br_ = car##pb, bi_ = cai##pb; \
    car##pa = g0_*ar_ - g1_*ai_ + g2_*br_ - g3_*bi_; \
    cai##pa = g0_*ai_ + g1_*ar_ + g2_*bi_ + g3_*br_; \
    car##pb = g4_*ar_ - g5_*ai_ + g6_*br_ - g7_*bi_; \
    cai##pb = g4_*ai_ + g5_*ar_ + g6_*bi_ + g7_*br_; }

#define STL(b) { P[sBst + 272*(b)     ] = pkh(car##b.x, cai##b.x); \
                 P[sBst + 272*(b) + 17] = pkh(car##b.y, cai##b.y); \
                 P[sBst + 272*(b) + 34] = pkh(car##b.z, cai##b.z); \
                 P[sBst + 272*(b) + 51] = pkh(car##b.w, cai##b.w); }

#define ROD(b, r, comp) { const float p_ = car##b.comp*car##b.comp + cai##b.comp*cai##b.comp; \
    Sx += p_; \
    aq0 += ((b)&2) ? -p_ : p_;  aq1 += ((b)&1) ? -p_ : p_; \
    aq4 += ((r)&2) ? -p_ : p_;  aq5 += ((r)&1) ? -p_ : p_; }
#define ROB(b) ROD(b,0,x) ROD(b,1,y) ROD(b,2,z) ROD(b,3,w)

__global__ __launch_bounds__(TPB)
__attribute__((amdgpu_waves_per_eu(4, 4)))
void vq_main(const float* __restrict__ x, const uint4* __restrict__ frag,
             const float* __restrict__ qcoef, float* __restrict__ out) {
    __shared__ unsigned pl[4][1088];   // wave-private planes, 4352 B each
    const int tid = threadIdx.x, wv = tid >> 6, lane = tid & 63;
    unsigned* P = pl[wv];
    const int elem = __builtin_amdgcn_readfirstlane(blockIdx.x * 4 + wv);
    const int n = lane & 15, quad = lane >> 4;
    const unsigned psel = (lane & 32) ? 0x07060302u : 0x05040100u;

    // perm addressing: P(k) = P(n*16) ^ P(b*256) ^ P(jb) ^ P(i)
    int Pn = 0;
#pragma unroll
    for (int mm = 0; mm < 4; ++mm)
        Pn ^= ((n >> mm) & 1) ? cnot_chain_ce(16 << mm) : 0;
    const int PBv = Pn ^ ((quad & 1) ? cnot_chain_ce(8) : 0);
    const int sB   = n + 17 * ((quad & 1) * 8);   // stage-B load base
    const int sAst = 17*n + 4*quad;               // stage-A store base
    const int sBst = 68*quad + n;                 // stage-B store base

    // ---- init: plain product state (perm is applied by the stage-A gather)
    const float* xr = x + elem * NQ;
    FORALLQ(DECLF)
    FORALLQ(MKF)
    {
        const float pr = (((lane>>5)&1) ? f1_0 : f0_0) * (((lane>>4)&1) ? f1_1 : f0_1)
                       * (((lane>>3)&1) ? f1_2 : f0_2) * (((lane>>2)&1) ? f1_3 : f0_3)
                       * (((lane>>1)&1) ? f1_4 : f0_4) * ((lane&1) ? f1_5 : f0_5);
        FORALL16(IST)
    }

    f32x4 car0, car1, car2, car3, cai0, cai1, cai2, cai3;
    const f32x4 z4 = {0.f, 0.f, 0.f, 0.f};

#pragma unroll 1
    for (int l = 0; l < NL; ++l) {
        const uint4* fp = frag + l*4*64;
        const f16x8 aAr = __builtin_bit_cast(f16x8, fp[lane]);
        const f16x8 aAi = __builtin_bit_cast(f16x8, fp[64 + lane]);
        const f16x8 aBr = __builtin_bit_cast(f16x8, fp[128 + lane]);
        const f16x8 aBi = __builtin_bit_cast(f16x8, fp[192 + lane]);
        const float* qc = qcoef + l*16;
        unsigned dw0, dw1, dw2, dw3, dw4, dw5, dw6, dw7;
        f16x8 fr0, fr1, fr2, fr3;

        // stage A: gather (perm fused) ALL blocks, then MFMA+store (in-place safe)
        GATH(0) GATH(1) GATH(2) GATH(3)
        __builtin_amdgcn_wave_barrier();
        MMA_A(0) MMA_A(1) MMA_A(2) MMA_A(3)
        __builtin_amdgcn_wave_barrier();

        // stage B: load all blocks, MFMA, qubit-0/1 register gates
        GATB(0) GATB(1) GATB(2) GATB(3)
        __builtin_amdgcn_wave_barrier();
        MMA_B(0) MMA_B(1) MMA_B(2) MMA_B(3)
        CGATE(0, 1, qc + 8)  CGATE(2, 3, qc + 8)   // qubit 1 (t_hi bit0)
        CGATE(0, 2, qc)      CGATE(1, 3, qc)       // qubit 0 (t_hi bit1)
        if (l < NL - 1) { STL(0) STL(1) STL(2) STL(3) }
    }

    // ---- readout from C regs: k = (b*16 + quad*4 + reg)*16 + n
    float Sx = 0.f, aq0 = 0.f, aq1 = 0.f, aq4 = 0.f, aq5 = 0.f;
    ROB(0) ROB(1) ROB(2) ROB(3)
    float w2 = ((lane>>5)&1) ? -Sx : Sx;
    float w3 = ((lane>>4)&1) ? -Sx : Sx;
    float w6 = ((lane>>3)&1) ? -Sx : Sx;
    float w7 = ((lane>>2)&1) ? -Sx : Sx;
    float w8 = ((lane>>1)&1) ? -Sx : Sx;
    float w9 = (lane&1) ? -Sx : Sx;
    WRED(aq0) WRED(aq1) WRED(w2) WRED(w3) WRED(aq4)
    WRED(aq5) WRED(w6) WRED(w7) WRED(w8) WRED(w9)
    if (lane == 0) {
        float* op = out + elem * NQ;
        op[0] = aq0; op[1] = aq1; op[2] = w2; op[3] = w3; op[4] = aq4;
        op[5] = aq5; op[6] = w6; op[7] = w7; op[8] = w8; op[9] = w9;
    }
}

extern "C" void kernel_launch(void* const* d_in, const int* in_sizes, int n_in,
                              void* d_out, int out_size, void* d_ws, size_t ws_size,
                              hipStream_t stream) {
    const float* x = (const float*)d_in[0];   // (16384, 10) fp32
    const float* w = (const float*)d_in[1];   // (3, 10, 3) fp32
    float* out = (float*)d_out;               // (16384, 10) fp32
    uint4* frag = (uint4*)d_ws;               // 768 uint4 = 12 KB A-fragments
    float* qcoef = (float*)((char*)d_ws + 768 * sizeof(uint4));   // 48 floats
    const int B = in_sizes[0] / NQ;           // 16384
    vq_prep<<<dim3(1), dim3(TPB), 0, stream>>>(w, frag, qcoef);
    vq_main<<<dim3(B / 4), dim3(TPB), 0, stream>>>(x, frag, qcoef, out);
}

// Round 13
// 99.874 us; speedup vs baseline: 2.3155x; 1.0506x over previous
//
#include <hip/hip_runtime.h>
#include <math.h>

#define NQ 10
#define NL 3
#define PI_F 3.14159265358979f
#define TPB 256   // 4 waves/block; ONE batch element per wave

typedef _Float16 f16x8 __attribute__((ext_vector_type(8)));
typedef _Float16 h2t  __attribute__((ext_vector_type(2)));
typedef float    f32x4 __attribute__((ext_vector_type(4)));

// Compiler memory barrier + LDS drain: optimizer cannot move LDS ops across,
// hardware guarantees all prior DS ops complete. (wave_barrier is NOT a memory
// fence — R11/R12 failed because typed loads were hoisted across stores.)
#define LDSFENCE asm volatile("s_waitcnt lgkmcnt(0)" ::: "memory")

// Composed CNOT-ring permutation (GF(2)-linear), compile-time only.
__host__ __device__ constexpr int cnot_chain_ce(int j) {
    for (int i = NQ - 1; i >= 0; --i) {
        int tq = (i + 1) % NQ;
        j ^= ((j >> (NQ - 1 - i)) & 1) << (NQ - 1 - tq);
    }
    return j;
}

__device__ __forceinline__ unsigned pkh(float r, float i) {
    return __builtin_bit_cast(unsigned, __builtin_amdgcn_cvt_pkrtz(r, i));
}

// Build a B-fragment (f16x8): element e = selected f16 half of dw[e].
// psel picks lo halves (re-plane lanes) or hi halves (im-plane lanes).
__device__ __forceinline__ f16x8 mkfrag(unsigned d0, unsigned d1, unsigned d2,
                                        unsigned d3, unsigned d4, unsigned d5,
                                        unsigned d6, unsigned d7, unsigned sel) {
    uint4 u;
    u.x = __builtin_amdgcn_perm(d1, d0, sel);
    u.y = __builtin_amdgcn_perm(d3, d2, sel);
    u.z = __builtin_amdgcn_perm(d5, d4, sel);
    u.w = __builtin_amdgcn_perm(d7, d6, sel);
    return __builtin_bit_cast(f16x8, u);
}

// lane-xor exchange for the final reduction: 1,2,4,8 DPP; 16 swizzle; 32 shfl
template<int MASK>
__device__ __forceinline__ unsigned lxu(unsigned v) {
    if constexpr (MASK == 1)
        return (unsigned)__builtin_amdgcn_update_dpp(0, (int)v, 0xB1, 0xF, 0xF, true);
    else if constexpr (MASK == 2)
        return (unsigned)__builtin_amdgcn_update_dpp(0, (int)v, 0x4E, 0xF, 0xF, true);
    else if constexpr (MASK == 4) {
        int a = __builtin_amdgcn_update_dpp(0, (int)v, 0x1B, 0xF, 0xF, true);
        return (unsigned)__builtin_amdgcn_update_dpp(0, a, 0x141, 0xF, 0xF, true);
    } else if constexpr (MASK == 8) {
        int a = __builtin_amdgcn_update_dpp(0, (int)v, 0x141, 0xF, 0xF, true);
        return (unsigned)__builtin_amdgcn_update_dpp(0, a, 0x140, 0xF, 0xF, true);
    } else if constexpr (MASK == 16)
        return (unsigned)__builtin_amdgcn_ds_swizzle((int)v, 0x401F);
    else
        return (unsigned)__shfl_xor((int)v, 32, 64);
}
#define WR1(v, M) v += __builtin_bit_cast(float, lxu<M>(__builtin_bit_cast(unsigned, v)));
#define WRED(v) { WR1(v,1) WR1(v,2) WR1(v,4) WR1(v,8) WR1(v,16) WR1(v,32) }

#define FORALL16(F) F(0) F(1) F(2) F(3) F(4) F(5) F(6) F(7) \
                    F(8) F(9) F(10) F(11) F(12) F(13) F(14) F(15)
#define FORALLQ(F) F(0) F(1) F(2) F(3) F(4) F(5) F(6) F(7) F(8) F(9)

// ============ prep: fused gate matrices -> MFMA A-fragments (R10-verified) ============
__global__ void vq_prep(const float* __restrict__ w, uint4* __restrict__ frag,
                        float* __restrict__ qcoef) {
    __shared__ float msh[NL * NQ][8];
    const int tid = threadIdx.x;
    if (tid < NL * NQ) {
        const float* wp = w + tid * 3;
        float sa = __sinf(wp[0]*0.5f), ca = __cosf(wp[0]*0.5f);
        float sb = __sinf(wp[1]*0.5f), cb = __cosf(wp[1]*0.5f);
        float sc = __sinf(wp[2]*0.5f), cc = __cosf(wp[2]*0.5f);
        float c00r = cb*ca,  c00i =  sa*sb;
        float c01r = -sb*ca, c01i = -cb*sa;
        float c10r =  sb*ca, c10i = -cb*sa;
        float c11r =  cb*ca, c11i = -sb*sa;
        float m[8];
        m[0] = cc*c00r + sc*c00i;  m[1] = cc*c00i - sc*c00r;
        m[2] = cc*c01r + sc*c01i;  m[3] = cc*c01i - sc*c01r;
        m[4] = cc*c10r - sc*c10i;  m[5] = cc*c10i + sc*c10r;
        m[6] = cc*c11r - sc*c11i;  m[7] = cc*c11i + sc*c11r;
#pragma unroll
        for (int j = 0; j < 8; ++j) msh[tid][j] = m[j];
        const int l = tid / NQ, q = tid % NQ;
        if (q < 2)
#pragma unroll
            for (int j = 0; j < 8; ++j) qcoef[(l*2 + q)*8 + j] = m[j];
    }
    __syncthreads();
    const int lane = tid & 63, wg = tid >> 6;
    const int mrow = lane & 15, quad = lane >> 4;
#pragma unroll 1
    for (int c = 0; c < 3; ++c) {
        const int id = c*4 + wg;            // id = l*4 + s*2 + v
        const int l = id >> 2, s = (id >> 1) & 1, v = id & 1;
        const int qb = s ? 2 : 6;
        unsigned pd[4];
#pragma unroll
        for (int d = 0; d < 4; ++d) {
            float hv[2];
#pragma unroll
            for (int h = 0; h < 2; ++h) {
                const int k = quad*8 + 2*d + h;
                const int col = k & 15;
                float er = 1.f, ei = 0.f;
#pragma unroll
                for (int p = 0; p < 4; ++p) {
                    const float* mm = msh[l*NQ + qb + p];
                    const int rb = (mrow >> (3-p)) & 1, cb2 = (col >> (3-p)) & 1;
                    const float gr = mm[(rb*2 + cb2)*2], gi = mm[(rb*2 + cb2)*2 + 1];
                    const float nr = er*gr - ei*gi, ni = er*gi + ei*gr;
                    er = nr; ei = ni;
                }
                hv[h] = (k < 16) ? (v ? ei : er) : (v ? er : -ei);
            }
            h2t hh; hh.x = (_Float16)hv[0]; hh.y = (_Float16)hv[1];
            pd[d] = __builtin_bit_cast(unsigned, hh);
        }
        frag[id*64 + lane] = make_uint4(pd[0], pd[1], pd[2], pd[3]);
    }
}

// ============ main kernel ============
// S  (inter-layer): R10-verified slot(k) = k + (k>>4), perm applied at GATH read.
// S' (intra-layer): j'-major slot = 68*j' + t. ALL LDS accesses are `unsigned`
// (single TBAA type) + LDSFENCE at every store->load boundary.

#define DECLF(q) float f0_##q, f1_##q;
#define MKF(q) { float e_ = __expf(2.0f * xr[q]); \
    float h_ = (1.0f - 2.0f / (e_ + 1.0f)) * (PI_F * 0.5f); \
    f1_##q = __sinf(h_); f0_##q = __cosf(h_); }

#define IST(J) { float a_ = pr \
    * ((((J) >> 3) & 1) ? f1_6 : f0_6) * ((((J) >> 2) & 1) ? f1_7 : f0_7) \
    * ((((J) >> 1) & 1) ? f1_8 : f0_8) * (((J) & 1) ? f1_9 : f0_9); \
    P[17*lane + (J)] = pkh(a_, 0.0f); }

// stage-A gather with perm fused (R10-verified): k = 256b + 16n + 8q1 + i
#define LDA1(b,i) { constexpr int pc_ = cnot_chain_ce((b)*256) ^ cnot_chain_ce(i); \
    const int pk_ = PBv ^ pc_; dw##i = P[pk_ + (pk_ >> 4)]; }
#define GATH(b) LDA1(b,0) LDA1(b,1) LDA1(b,2) LDA1(b,3) LDA1(b,4) LDA1(b,5) LDA1(b,6) LDA1(b,7) \
    fr##b = mkfrag(dw0,dw1,dw2,dw3,dw4,dw5,dw6,dw7,psel);

// stage-A MFMA + store to S' (j'-major): slot = 68*(4quad+r) + 16b + n
// per-instruction bank = (16*quad + n) mod 32 -> exact 2-way, free
#define MMA_A(b) { \
    f32x4 cr_ = __builtin_amdgcn_mfma_f32_16x16x32_f16(aAr, fr##b, z4, 0, 0, 0); \
    f32x4 ci_ = __builtin_amdgcn_mfma_f32_16x16x32_f16(aAi, fr##b, z4, 0, 0, 0); \
    P[sA + 16*(b)      ] = pkh(cr_.x, ci_.x); \
    P[sA + 16*(b) +  68] = pkh(cr_.y, ci_.y); \
    P[sA + 16*(b) + 136] = pkh(cr_.z, ci_.z); \
    P[sA + 16*(b) + 204] = pkh(cr_.w, ci_.w); }

// stage-B gather: 8 ADJACENT unsigned loads (slot = 68n + 8q1 + 16b + i) --
// same TBAA type as all stores; backend may fuse into ds_read_b128.
#define GATB(b) { const int gb_ = 68*n + 8*q1 + 16*(b); \
    dw0 = P[gb_    ]; dw1 = P[gb_ + 1]; dw2 = P[gb_ + 2]; dw3 = P[gb_ + 3]; \
    dw4 = P[gb_ + 4]; dw5 = P[gb_ + 5]; dw6 = P[gb_ + 6]; dw7 = P[gb_ + 7]; \
    fr##b = mkfrag(dw0,dw1,dw2,dw3,dw4,dw5,dw6,dw7,psel); }

#define MMA_B(b) \
    car##b = __builtin_amdgcn_mfma_f32_16x16x32_f16(aBr, fr##b, z4, 0, 0, 0); \
    cai##b = __builtin_amdgcn_mfma_f32_16x16x32_f16(aBi, fr##b, z4, 0, 0, 0);

// complex 2x2 gate on C-accumulator block pair (f32)
#define CGATE(pa, pb, qp) { \
    const float g0_=(qp)[0], g1_=(qp)[1], g2_=(qp)[2], g3_=(qp)[3]; \
    const float g4_=(qp)[4], g5_=(qp)[5], g6_=(qp)[6], g7_=(qp)[7]; \
    f32x4 ar_ = car##pa, ai_ = cai##pa, br_ = car##pb, bi_ = cai##pb; \
    car##pa = g0_*ar_ - g1_*ai_ + g2_*br_ - g3_*bi_; \
    cai##pa = g0_*ai_ + g1_*ar_ + g2_*bi_ + g3_*br_; \
    car##pb = g4_*ar_ - g5_*ai_ + g6_*br_ - g7_*bi_; \
    cai##pb = g4_*ai_ + g5_*ar_ + g6_*bi_ + g7_*br_; }

// layer store to S, natural order (R10-verified): k_out = 256b + 64quad + 16r + n
#define STL(b) { P[sBst + 272*(b)     ] = pkh(car##b.x, cai##b.x); \
                 P[sBst + 272*(b) + 17] = pkh(car##b.y, cai##b.y); \
                 P[sBst + 272*(b) + 34] = pkh(car##b.z, cai##b.z); \
                 P[sBst + 272*(b) + 51] = pkh(car##b.w, cai##b.w); }

#define ROD(b, r, comp) { const float p_ = car##b.comp*car##b.comp + cai##b.comp*cai##b.comp; \
    Sx += p_; \
    aq0 += ((b)&2) ? -p_ : p_;  aq1 += ((b)&1) ? -p_ : p_; \
    aq4 += ((r)&2) ? -p_ : p_;  aq5 += ((r)&1) ? -p_ : p_; }
#define ROB(b) ROD(b,0,x) ROD(b,1,y) ROD(b,2,z) ROD(b,3,w)

__global__ __launch_bounds__(TPB)
__attribute__((amdgpu_waves_per_eu(4, 4)))
void vq_main(const float* __restrict__ x, const uint4* __restrict__ frag,
             const float* __restrict__ qcoef, float* __restrict__ out) {
    __shared__ __align__(16) unsigned pl[4][1088];   // wave-private planes
    const int tid = threadIdx.x, wv = tid >> 6, lane = tid & 63;
    unsigned* P = pl[wv];
    const int elem = __builtin_amdgcn_readfirstlane(blockIdx.x * 4 + wv);
    const int n = lane & 15, quad = lane >> 4, q1 = quad & 1;
    const unsigned psel = (lane & 32) ? 0x07060302u : 0x05040100u;

    // perm addressing (R10-verified): P(k) = P(16n) ^ P(8q1) ^ P(256b) ^ P(i)
    int Pn = 0;
#pragma unroll
    for (int mm = 0; mm < 4; ++mm)
        Pn ^= ((n >> mm) & 1) ? cnot_chain_ce(16 << mm) : 0;
    const int PBv = Pn ^ (q1 ? cnot_chain_ce(8) : 0);
    const int sA   = 272*quad + n;                // stage-A store base (S')
    const int sBst = 68*quad + n;                 // layer store base (S)

    // ---- init: plain product state at slot(k)=k+(k>>4) (perm applied at GATH)
    const float* xr = x + elem * NQ;
    FORALLQ(DECLF)
    FORALLQ(MKF)
    {
        const float pr = (((lane>>5)&1) ? f1_0 : f0_0) * (((lane>>4)&1) ? f1_1 : f0_1)
                       * (((lane>>3)&1) ? f1_2 : f0_2) * (((lane>>2)&1) ? f1_3 : f0_3)
                       * (((lane>>1)&1) ? f1_4 : f0_4) * ((lane&1) ? f1_5 : f0_5);
        FORALL16(IST)
    }
    LDSFENCE;

    f32x4 car0, car1, car2, car3, cai0, cai1, cai2, cai3;
    const f32x4 z4 = {0.f, 0.f, 0.f, 0.f};

#pragma unroll 1
    for (int l = 0; l < NL; ++l) {
        const uint4* fp = frag + l*4*64;
        const f16x8 aAr = __builtin_bit_cast(f16x8, fp[lane]);
        const f16x8 aAi = __builtin_bit_cast(f16x8, fp[64 + lane]);
        const f16x8 aBr = __builtin_bit_cast(f16x8, fp[128 + lane]);
        const f16x8 aBi = __builtin_bit_cast(f16x8, fp[192 + lane]);
        const float* qc = qcoef + l*16;
        unsigned dw0, dw1, dw2, dw3, dw4, dw5, dw6, dw7;
        f16x8 fr0, fr1, fr2, fr3;

        // stage A: gather (perm fused) ALL blocks, then MFMA+store into S'
        GATH(0) GATH(1) GATH(2) GATH(3)
        LDSFENCE;                          // all S reads done before S' overwrites
        MMA_A(0) MMA_A(1) MMA_A(2) MMA_A(3)
        LDSFENCE;                          // S' stores done before S' reads

        // stage B: adjacent loads from S', MFMA, qubit-0/1 register gates
        GATB(0) GATB(1) GATB(2) GATB(3)
        LDSFENCE;                          // S' reads done before STL overwrites
        MMA_B(0) MMA_B(1) MMA_B(2) MMA_B(3)
        CGATE(0, 1, qc + 8)  CGATE(2, 3, qc + 8)   // qubit 1 (t_hi bit0)
        CGATE(0, 2, qc)      CGATE(1, 3, qc)       // qubit 0 (t_hi bit1)
        if (l < NL - 1) {
            STL(0) STL(1) STL(2) STL(3)            // natural-order store into S
            LDSFENCE;                      // S stores done before next GATH
        }
    }

    // ---- readout from C regs: k = (16b + 4quad + r)*16 + n
    float Sx = 0.f, aq0 = 0.f, aq1 = 0.f, aq4 = 0.f, aq5 = 0.f;
    ROB(0) ROB(1) ROB(2) ROB(3)
    float w2 = ((lane>>5)&1) ? -Sx : Sx;
    float w3 = ((lane>>4)&1) ? -Sx : Sx;
    float w6 = ((lane>>3)&1) ? -Sx : Sx;
    float w7 = ((lane>>2)&1) ? -Sx : Sx;
    float w8 = ((lane>>1)&1) ? -Sx : Sx;
    float w9 = (lane&1) ? -Sx : Sx;
    WRED(aq0) WRED(aq1) WRED(w2) WRED(w3) WRED(aq4)
    WRED(aq5) WRED(w6) WRED(w7) WRED(w8) WRED(w9)
    if (lane == 0) {
        float* op = out + elem * NQ;
        op[0] = aq0; op[1] = aq1; op[2] = w2; op[3] = w3; op[4] = aq4;
        op[5] = aq5; op[6] = w6; op[7] = w7; op[8] = w8; op[9] = w9;
    }
}

extern "C" void kernel_launch(void* const* d_in, const int* in_sizes, int n_in,
                              void* d_out, int out_size, void* d_ws, size_t ws_size,
                              hipStream_t stream) {
    const float* x = (const float*)d_in[0];   // (16384, 10) fp32
    const float* w = (const float*)d_in[1];   // (3, 10, 3) fp32
    float* out = (float*)d_out;               // (16384, 10) fp32
    uint4* frag = (uint4*)d_ws;               // 768 uint4 = 12 KB A-fragments
    float* qcoef = (float*)((char*)d_ws + 768 * sizeof(uint4));   // 48 floats
    const int B = in_sizes[0] / NQ;           // 16384
    vq_prep<<<dim3(1), dim3(TPB), 0, stream>>>(w, frag, qcoef);
    vq_main<<<dim3(B / 4), dim3(TPB), 0, stream>>>(x, frag, qcoef, out);
}